// Round 18
// baseline (499.679 us; speedup 1.0000x reference)
//
#include <hip/hip_runtime.h>

#define INF_F __builtin_inff()

typedef __attribute__((ext_vector_type(8))) short short8v;  // 8 bf16
typedef __attribute__((ext_vector_type(4))) float f32x4;
typedef unsigned long long ull;

__device__ __forceinline__ short f2bf(float x) {
  const unsigned u = __float_as_uint(x);
  return (short)((u + 0x7FFFu + ((u >> 16) & 1u)) >> 16);   // RNE
}

__device__ __forceinline__ unsigned mbcnt64(ull m) {
  return __builtin_amdgcn_mbcnt_hi((unsigned)(m >> 32),
                                   __builtin_amdgcn_mbcnt_lo((unsigned)m, 0u));
}

// ===========================================================================
// Spatial-bin exact kNN, WAVE-per-target, G=5, materialized flat positions,
// per-target face bound for escalation (round-13..17 config, measured ~73 us).
// ===========================================================================
#define KNN_G 5
#define KNN_NC (KNN_G*KNN_G*KNN_G*KNN_G)   // 625
#define KNN_PCAP 1600

// ---- merged init kernels ---------------------------------------------------
__global__ __launch_bounds__(256) void count2_kernel(
    const float* __restrict__ loc, int* __restrict__ cellcount,
    int* __restrict__ cellid, int n,
    const int* __restrict__ dst, int* __restrict__ deg, int E)
{
  const int i = blockIdx.x * 256 + threadIdx.x;
  if (i < n) {
    const float4 l = *(const float4*)(loc + (size_t)i*4);
    const int cx = min(KNN_G-1, (int)(l.x * (float)KNN_G));
    const int cy = min(KNN_G-1, (int)(l.y * (float)KNN_G));
    const int cz = min(KNN_G-1, (int)(l.z * (float)KNN_G));
    const int cw = min(KNN_G-1, (int)(l.w * (float)KNN_G));
    const int c = ((cx*KNN_G + cy)*KNN_G + cz)*KNN_G + cw;
    cellid[i] = c;
    atomicAdd(&cellcount[c], 1);
  }
  if (i < E) atomicAdd(&deg[dst[i]], 1);
}

__device__ __forceinline__ void scan1b_body(
    const int* __restrict__ in, int* __restrict__ out, int n, int per)
{
  __shared__ int part[1024];
  const int t = threadIdx.x;
  const int lo = t * per, hi = min(lo + per, n);
  int sum = 0;
  for (int idx = lo; idx < hi; ++idx) sum += in[idx];
  int v = sum;
  part[t] = v;
  __syncthreads();
  for (int off = 1; off < 1024; off <<= 1) {
    const int o = (t >= off) ? part[t - off] : 0;
    __syncthreads();
    v += o;
    part[t] = v;
    __syncthreads();
  }
  int run = v - sum;
  for (int idx = lo; idx < hi; ++idx) { out[idx] = run; run += in[idx]; }
  if (t == 1023) out[n] = v;
}

__global__ __launch_bounds__(1024) void scan2_kernel(
    const int* __restrict__ inA, int* __restrict__ outA, int nA, int perA,
    const int* __restrict__ inB, int* __restrict__ outB, int nB, int perB)
{
  if (blockIdx.x == 0) scan1b_body(inA, outA, nA, perA);
  else                 scan1b_body(inB, outB, nB, perB);
}

__global__ __launch_bounds__(256) void scatter2_kernel(
    const float* __restrict__ loc, const int* __restrict__ cellid,
    const int* __restrict__ cellstart, int* __restrict__ cellfill,
    float* __restrict__ locs4s, int* __restrict__ oidx, int n,
    const int* __restrict__ srcs, const int* __restrict__ dsts,
    const int* __restrict__ rowptr, int* __restrict__ dfill,
    int* __restrict__ cs_src, int* __restrict__ cs_eid, int E)
{
  const int i = blockIdx.x * 256 + threadIdx.x;
  if (i < n) {
    const int c = cellid[i];
    const int pos = cellstart[c] + atomicAdd(&cellfill[c], 1);
    *(float4*)(locs4s + (size_t)pos*4) = *(const float4*)(loc + (size_t)i*4);
    oidx[pos] = i;
  }
  if (i < E) {
    const int d = dsts[i];
    const int pos = rowptr[d] + atomicAdd(&dfill[d], 1);
    cs_src[pos] = srcs[i];
    cs_eid[pos] = i;
  }
}

// ---- kNN selection helpers -------------------------------------------------
__device__ __forceinline__ ull
knn_refine16(ull* __restrict__ B, int cnt, int lane, ull& topsave)
{
  ull v[5];
#pragma unroll
  for (int s = 0; s < 5; ++s) {
    const int idx = lane + 64*s;
    v[s] = (idx < cnt) ? B[idx] : ~0ull;
  }
  ull tau = ~0ull;
#pragma unroll
  for (int r = 0; r < 16; ++r) {
    ull m = v[0]; int sl = 0;
#pragma unroll
    for (int s = 1; s < 5; ++s) if (v[s] < m) { m = v[s]; sl = s; }
    ull mm = m;
#pragma unroll
    for (int off = 32; off >= 1; off >>= 1) {
      const ull o = __shfl_xor(mm, off, 64);
      if (o < mm) mm = o;
    }
    const bool killer = (m == mm);
#pragma unroll
    for (int s = 0; s < 5; ++s) if (killer && sl == s) v[s] = ~0ull;
    if (lane == r) topsave = mm;
    tau = mm;            // after round 15: exact 16th-smallest
  }
  if (lane < 16) B[lane] = topsave;
  return tau;
}

__device__ __forceinline__ int
knn_filter(ull* __restrict__ B, int cnt, int lane, ull& tau)
{
  ull v[5];
#pragma unroll
  for (int s = 0; s < 5; ++s) {
    const int idx = lane + 64*s;
    v[s] = (idx < cnt) ? B[idx] : ~0ull;
  }
  ull g = v[0];
#pragma unroll
  for (int s = 1; s < 5; ++s) if (v[s] < g) g = v[s];
  { ull o = __shfl_xor(g, 1, 64); if (o < g) g = o;
    o = __shfl_xor(g, 2, 64); if (o < g) g = o; }
  ull t = g;
#pragma unroll
  for (int off = 4; off <= 32; off <<= 1) {
    const ull o = __shfl_xor(t, off, 64);
    if (o > t) t = o;
  }
  int nc = 0;
#pragma unroll
  for (int s = 0; s < 5; ++s) {
    const bool keep = (v[s] <= t) && (v[s] != ~0ull);
    const ull mask = __ballot(keep);
    if (mask) {
      const unsigned pre = mbcnt64(mask);
      if (keep) B[nc + pre] = v[s];
      nc += (int)__popcll(mask);
    }
  }
  tau = t;
  return nc;
}

__device__ void knn_body(int blk, ull* __restrict__ Bs, int* __restrict__ PosAll,
                         const float* __restrict__ locs4s,
                         const int* __restrict__ oidx,
                         const int* __restrict__ cellstart,
                         int* __restrict__ knn, int n)
{
#pragma clang fp contract(off)
  constexpr int TRIG = 256;
  const int wave = threadIdx.x >> 6, lane = threadIdx.x & 63;
  const int t = blk * 4 + wave;          // sorted position of target
  if (t >= n) return;                    // wave-uniform exit
  ull* B = Bs + wave * 320;
  int* Pos = PosAll + wave * KNN_PCAP;

  const float4 L = *(const float4*)(locs4s + (size_t)t*4);
  const float tx = L.x, ty = L.y, tz = L.z, tw = L.w;
  const int cx = min(KNN_G-1, (int)(tx * (float)KNN_G));
  const int cy = min(KNN_G-1, (int)(ty * (float)KNN_G));
  const int cz = min(KNN_G-1, (int)(tz * (float)KNN_G));
  const int cw = min(KNN_G-1, (int)(tw * (float)KNN_G));

  ull tau = ~0ull;
  ull topsave = ~0ull;
  int cnt = 0;

  auto boundB = [&](int mr) -> float {
    const float w = 1.0f / (float)KNN_G;
    float Bv = INF_F;
    if (cx - mr >= 1)         Bv = fminf(Bv, tx - (float)(cx - mr) * w);
    if (cx + mr <= KNN_G - 2) Bv = fminf(Bv, (float)(cx + mr + 1) * w - tx);
    if (cy - mr >= 1)         Bv = fminf(Bv, ty - (float)(cy - mr) * w);
    if (cy + mr <= KNN_G - 2) Bv = fminf(Bv, (float)(cy + mr + 1) * w - ty);
    if (cz - mr >= 1)         Bv = fminf(Bv, tz - (float)(cz - mr) * w);
    if (cz + mr <= KNN_G - 2) Bv = fminf(Bv, (float)(cz + mr + 1) * w - tz);
    if (cw - mr >= 1)         Bv = fminf(Bv, tw - (float)(cw - mr) * w);
    if (cw + mr <= KNN_G - 2) Bv = fminf(Bv, (float)(cw + mr + 1) * w - tw);
    return Bv;
  };

  auto do_range = [&](int ps, int pe) {
    for (int p0 = ps; p0 < pe; p0 += 64) {
      const int p = p0 + lane;
      ull key = ~0ull;
      if (p < pe && p != t) {
        const float4 q = *(const float4*)(locs4s + (size_t)p*4);
        const int oj = oidx[p];
        const float a0 = q.x - tx, a1 = q.y - ty, a2 = q.z - tz, a3 = q.w - tw;
        const float s0 = a0*a0, s1 = a1*a1, s2 = a2*a2, s3 = a3*a3;
        const float d = ((s0 + s1) + s2) + s3;
        key = ((ull)__float_as_uint(d) << 32) | (unsigned)oj;
      }
      const bool surv = key < tau;
      const ull mask = __ballot(surv);
      if (mask) {
        const unsigned pre = mbcnt64(mask);
        if (surv) B[cnt + pre] = key;
        cnt += (int)__popcll(mask);
        if (cnt > TRIG) cnt = knn_filter(B, cnt, lane, tau);
      }
    }
  };

  // ---- level 0: radius-1 block as a materialized flat position list ----
  int psv = 0, pev = 0;
  if (lane < 27) {
    const int cr = (lane == 0) ? 13 : (lane <= 13 ? lane - 1 : lane);
    const int ax = cx + (cr / 9) - 1;
    const int ay = cy + ((cr / 3) % 3) - 1;
    const int az = cz + (cr % 3) - 1;
    if (ax >= 0 && ax < KNN_G && ay >= 0 && ay < KNN_G &&
        az >= 0 && az < KNN_G) {
      const int base = ((ax*KNN_G + ay)*KNN_G + az)*KNN_G;
      const int wlo = max(cw-1, 0), whi = min(cw+1, KNN_G-1);
      psv = cellstart[base + wlo];
      pev = cellstart[base + whi + 1];
    }
  }
  const int len = max(pev - psv, 0);
  int cum = len;
#pragma unroll
  for (int off = 1; off < 64; off <<= 1) {
    const int o = __shfl_up(cum, off, 64);
    if (lane >= off) cum += o;
  }
  const int T = __shfl(cum, 63, 64);
  const int startv = cum - len;

  for (int p = psv, f = startv; p < pev && f < KNN_PCAP; ++p, ++f) Pos[f] = p;

  const int Tb = min(T, KNN_PCAP);
  const int Tm1b = Tb - 1;
  float4 qn; int ojn = 0, pgn = 0; bool vn = false;
  {
    vn = lane < Tb;
    pgn = Pos[min(lane, Tm1b)];
    qn = *(const float4*)(locs4s + (size_t)pgn*4);
    ojn = oidx[pgn];
  }
  for (int f0 = 0; f0 < Tb; f0 += 64) {
    const float4 qc = qn; const int ojc = ojn, pgc = pgn; const bool vc = vn;
    const int fN = f0 + 64 + lane;
    vn = fN < Tb;
    if (f0 + 64 < Tb) {
      pgn = Pos[min(fN, Tm1b)];
      qn = *(const float4*)(locs4s + (size_t)pgn*4);
      ojn = oidx[pgn];
    }
    ull key = ~0ull;
    if (vc && pgc != t) {
      const float a0 = qc.x - tx, a1 = qc.y - ty, a2 = qc.z - tz, a3 = qc.w - tw;
      const float s0 = a0*a0, s1 = a1*a1, s2 = a2*a2, s3 = a3*a3;
      const float d = ((s0 + s1) + s2) + s3;
      key = ((ull)__float_as_uint(d) << 32) | (unsigned)ojc;
    }
    const bool surv = key < tau;
    const ull mask = __ballot(surv);
    if (mask) {
      const unsigned pre = mbcnt64(mask);
      if (surv) B[cnt + pre] = key;
      cnt += (int)__popcll(mask);
      if (cnt > TRIG) cnt = knn_filter(B, cnt, lane, tau);
    }
  }
  if (T > KNN_PCAP) {
    for (int r = 0; r < 27; ++r) {
      const int st = __shfl(startv, r, 64);
      const int ps = __shfl(psv, r, 64);
      const int pe = __shfl(pev, r, 64);
      const int done = min(max(KNN_PCAP - st, 0), pe - ps);
      if (ps + done < pe) do_range(ps + done, pe);
    }
  }

  // ---- shells m = 2..G-1 (rare; exact refine + per-target bound check) ----
  for (int m = 2; m <= KNN_G - 1; ++m) {
    if (cnt > 16) { tau = knn_refine16(B, cnt, lane, topsave); cnt = 16; }
    if (tau != ~0ull) {
      const float taud = __uint_as_float((unsigned)(tau >> 32));
      const float Bv = boundB(m - 1);
      if (Bv == INF_F || taud < Bv * Bv * 0.99999f) break;
    }
    const int xlo = max(cx-m, 0), xhi = min(cx+m, KNN_G-1);
    for (int ax = xlo; ax <= xhi; ++ax) {
      const bool xe = (ax == cx-m) || (ax == cx+m);
      const int ylo = max(cy-m, 0), yhi = min(cy+m, KNN_G-1);
      for (int ay = ylo; ay <= yhi; ++ay) {
        const bool ye = (ay == cy-m) || (ay == cy+m);
        const int zlo = max(cz-m, 0), zhi = min(cz+m, KNN_G-1);
        for (int az = zlo; az <= zhi; ++az) {
          const bool ze = (az == cz-m) || (az == cz+m);
          const int base = ((ax*KNN_G + ay)*KNN_G + az)*KNN_G;
          if (xe | ye | ze) {
            const int wlo = max(cw-m, 0), whi = min(cw+m, KNN_G-1);
            do_range(cellstart[base+wlo], cellstart[base+whi+1]);
          } else {
            if (cw-m >= 0) {
              const int c = base + cw - m;
              do_range(cellstart[c], cellstart[c+1]);
            }
            if (cw+m <= KNN_G-1) {
              const int c = base + cw + m;
              do_range(cellstart[c], cellstart[c+1]);
            }
          }
        }
      }
    }
  }
  (void)knn_refine16(B, cnt, lane, topsave);   // exact top-16
  const int i = oidx[t];
  if (lane < 16) knn[(size_t)i*16 + lane] = (int)(topsave & 0xFFFFFFFFull);
}

// ---------------------------------------------------------------------------
// Staging helper: convert a 64x64 fp32 tile row-chunk to bf16 LDS (pitch 72).
// ---------------------------------------------------------------------------
__device__ __forceinline__ void stage_tile_bf16(
    short* __restrict__ S, const float* __restrict__ src, int srow, int sc16,
    bool valid)
{
  short tmp[16];
  if (valid) {
#pragma unroll
    for (int u = 0; u < 4; ++u) {
      const float4 v = *(const float4*)(src + u*4);
      tmp[u*4+0] = f2bf(v.x); tmp[u*4+1] = f2bf(v.y);
      tmp[u*4+2] = f2bf(v.z); tmp[u*4+3] = f2bf(v.w);
    }
  } else {
#pragma unroll
    for (int u = 0; u < 16; ++u) tmp[u] = 0;
  }
  *(short8v*)&S[srow*72 + sc16]     = *(short8v*)&tmp[0];
  *(short8v*)&S[srow*72 + sc16 + 8] = *(short8v*)&tmp[8];
}

// ---------------------------------------------------------------------------
// Msg phase helper: this wave computes agg rows [wave*16, wave*16+16) of the
// block's 64-row tile and writes f2bf(agg) into As (bit-identical to the old
// global-fp32-roundtrip + f2bf staging). Requires wm fragments + bm preloaded.
// ---------------------------------------------------------------------------
__device__ __forceinline__ void msg_phase(
    short* __restrict__ As,
    const float* __restrict__ R, const short* __restrict__ eac,
    const short8v* __restrict__ bfr, const float* __restrict__ bmv,
    const int* __restrict__ cs_src, const int* __restrict__ rowptr,
    int m0, int wave, int lane, int grp, int li, int M)
{
  const f32x4 zero = (f32x4)0.f;
  for (int tg = 0; tg < 16; ++tg) {
    const int d = m0 + wave*16 + tg;         // wave-uniform
    float vmax[4] = {0.f, 0.f, 0.f, 0.f};
    if (d < M) {
      const int beg = rowptr[d], end = rowptr[d+1];
      const int deg = end - beg;
      float basev[4];
#pragma unroll
      for (int nt = 0; nt < 4; ++nt)
        basev[nt] = bmv[nt] - R[(size_t)d*64 + nt*16 + li];
      for (int e0 = 0; e0 < deg; e0 += 16) {
        short8v a = (short8v)0;
        const int erow = e0 + li;
        if (grp < 2 && erow < deg)
          a = *(const short8v*)(eac + (size_t)(beg + erow)*16 + grp*8);
        f32x4 Dv[4];
#pragma unroll
        for (int nt = 0; nt < 4; ++nt)
          Dv[nt] = __builtin_amdgcn_mfma_f32_16x16x32_bf16(a, bfr[nt], zero, 0, 0, 0);
#pragma unroll
        for (int j = 0; j < 4; ++j) {
          const int m = e0 + grp*4 + j;
          if (m < deg) {
            const int s = cs_src[beg + m];
            const float* Rs = R + (size_t)s*64;
#pragma unroll
            for (int nt = 0; nt < 4; ++nt) {
              const float acc = Dv[nt][j] + Rs[nt*16 + li] + basev[nt];
              vmax[nt] = fmaxf(vmax[nt], fmaxf(acc, 0.f));
            }
          }
        }
      }
#pragma unroll
      for (int nt = 0; nt < 4; ++nt) {
        float mm = vmax[nt];
        mm = fmaxf(mm, __shfl_xor(mm, 16, 64));
        mm = fmaxf(mm, __shfl_xor(mm, 32, 64));
        vmax[nt] = mm;
      }
    }
    float r = vmax[0];
    r = (grp == 1) ? vmax[1] : r;
    r = (grp == 2) ? vmax[2] : r;
    r = (grp == 3) ? vmax[3] : r;
    As[(wave*16 + tg)*72 + lane] = f2bf(r);   // wave-local rows
  }
}

// load the per-wave wm fragments + bm values for the msg phase
__device__ __forceinline__ void msg_frags(
    const float* __restrict__ wm, const float* __restrict__ bm,
    short8v* __restrict__ bfr, float* __restrict__ bmv, int grp, int li)
{
#pragma unroll
  for (int nt = 0; nt < 4; ++nt) {
    short8v b = (short8v)0;
    if (grp < 2) {
      const int ch = nt*16 + li;
#pragma unroll
      for (int j = 0; j < 8; ++j) b[j] = f2bf(wm[ch*80 + grp*8 + j]);
    }
    bfr[nt] = b;
    bmv[nt] = bm[nt*16 + li];
  }
}

// ---------------------------------------------------------------------------
// Mega kernel: [0,KB) knn | [KB,KB+EB) ea permute->bf16 | [KB+EB,+64) pack |
// [KB+EB+64, +MB) R1 = x @ wm1[:,16:]^T  (bf16 MFMA).
// ---------------------------------------------------------------------------
__global__ __launch_bounds__(256) void mega_kernel(
    const float* __restrict__ locs4s, const int* __restrict__ oidx,
    const int* __restrict__ cellstart, int* __restrict__ knn, int n,
    const float* __restrict__ ea, const int* __restrict__ cs_eid,
    short* __restrict__ eac, int E,
    const float* __restrict__ w1A, const float* __restrict__ b1A,
    float* __restrict__ wpqA, float* __restrict__ bpqA,
    const float* __restrict__ w1B, const float* __restrict__ b1B,
    float* __restrict__ wpqB, float* __restrict__ bpqB,
    const float* __restrict__ x, const float* __restrict__ wm1,
    float* __restrict__ Rout,
    int KB, int EB)
{
  __shared__ __align__(16) char smem[4*320*8 + 4*KNN_PCAP*4];  // 35840 B
  const int bid = blockIdx.x;
  if (bid < KB) {
    knn_body(bid, (ull*)smem, (int*)(smem + 4*320*8),
             locs4s, oidx, cellstart, knn, n);
  } else if (bid < KB + EB) {
    const int e = (bid - KB) * 256 + threadIdx.x;
    if (e < E) {
      const float* src = ea + (size_t)cs_eid[e]*16;
      short tmp[16];
#pragma unroll
      for (int u = 0; u < 4; ++u) {
        const float4 v = *(const float4*)(src + u*4);
        tmp[u*4+0] = f2bf(v.x); tmp[u*4+1] = f2bf(v.y);
        tmp[u*4+2] = f2bf(v.z); tmp[u*4+3] = f2bf(v.w);
      }
      *(short8v*)(eac + (size_t)e*16)     = *(short8v*)&tmp[0];
      *(short8v*)(eac + (size_t)e*16 + 8) = *(short8v*)&tmp[8];
    }
  } else if (bid < KB + EB + 64) {
    const int gidx = (bid - KB - EB) * 256 + threadIdx.x;
    const int l = gidx >> 13;
    const int idx = gidx & 8191;
    const float* w1 = l ? w1B : w1A;
    const float* b1 = l ? b1B : b1A;
    float* wpq = l ? wpqB : wpqA;
    float* bpq = l ? bpqB : bpqA;
    const int o = idx >> 6, i = idx & 63;
    const float a = w1[o*128 + i], b = w1[o*128 + 64 + i];
    wpq[idx] = a - b;
    wpq[128*64 + idx] = b;
    if (idx < 128) { bpq[idx] = b1[idx]; bpq[128 + idx] = 0.f; }
  } else {
    // R1 GEMM: Rout = x @ wm1^T  (wm1 pre-offset +16, ld 80)
    short* As = (short*)smem;
    short* Ws = (short*)(smem + 64*72*2);
    const int tid = threadIdx.x;
    const int wave = tid >> 6, lane = tid & 63;
    const int grp = lane >> 4, li = lane & 15;
    const int m0 = (bid - KB - EB - 64) * 64;
    const int srow = tid >> 2;
    const int sc16 = (tid & 3) * 16;
    const int gr = m0 + srow;
    stage_tile_bf16(As, x + (size_t)gr*64 + sc16, srow, sc16, gr < n);
    stage_tile_bf16(Ws, wm1 + (size_t)srow*80 + sc16, srow, sc16, true);
    __syncthreads();
    f32x4 acc[4];
#pragma unroll
    for (int nt = 0; nt < 4; ++nt) acc[nt] = (f32x4)0.f;
#pragma unroll
    for (int ks = 0; ks < 2; ++ks) {
      const short8v a = *(const short8v*)&As[(wave*16 + li)*72 + ks*32 + grp*8];
#pragma unroll
      for (int nt = 0; nt < 4; ++nt) {
        const short8v b = *(const short8v*)&Ws[(nt*16 + li)*72 + ks*32 + grp*8];
        acc[nt] = __builtin_amdgcn_mfma_f32_16x16x32_bf16(a, b, acc[nt], 0, 0, 0);
      }
    }
#pragma unroll
    for (int nt = 0; nt < 4; ++nt) {
      const int ch = nt*16 + li;
#pragma unroll
      for (int j = 0; j < 4; ++j) {
        const int r = m0 + wave*16 + grp*4 + j;
        if (r < n) Rout[(size_t)r*64 + ch] = acc[nt][j];
      }
    }
  }
}

// ---------------------------------------------------------------------------
// Fused static layer: msg (into LDS) + h = relu(agg@Wu^T+bu) -> Hout AND
// R_next = bf16(h) @ bf16(Wm_next)^T -> Rout.  One dispatch per layer.
// ---------------------------------------------------------------------------
__global__ __launch_bounds__(256) void static_layer_kernel(
    const float* __restrict__ R, const short* __restrict__ eac,
    const float* __restrict__ wm, const float* __restrict__ bm,
    const int* __restrict__ cs_src, const int* __restrict__ rowptr,
    const float* __restrict__ Wu, const float* __restrict__ bu,
    float* __restrict__ Hout, int ldh,
    const float* __restrict__ Wm_next,            // pre-offset +16, ld 80
    float* __restrict__ Rout, int M)
{
  __shared__ short As[64 * 72];
  __shared__ short Ws[64 * 72];
  const int tid = threadIdx.x;
  const int wave = tid >> 6, lane = tid & 63;
  const int grp = lane >> 4, li = lane & 15;
  const int m0 = blockIdx.x * 64;
  const int srow = tid >> 2;
  const int sc16 = (tid & 3) * 16;

  // ---- msg phase -> As (bf16 agg tile) ----
  short8v bfr[4]; float bmv[4];
  msg_frags(wm, bm, bfr, bmv, grp, li);
  msg_phase(As, R, eac, bfr, bmv, cs_src, rowptr, m0, wave, lane, grp, li, M);

  // ---- h GEMM ----
  stage_tile_bf16(Ws, Wu + (size_t)srow*64 + sc16, srow, sc16, true);
  __syncthreads();
  f32x4 acc[4];
#pragma unroll
  for (int nt = 0; nt < 4; ++nt) acc[nt] = (f32x4)0.f;
#pragma unroll
  for (int ks = 0; ks < 2; ++ks) {
    const short8v a = *(const short8v*)&As[(wave*16 + li)*72 + ks*32 + grp*8];
#pragma unroll
    for (int nt = 0; nt < 4; ++nt) {
      const short8v b = *(const short8v*)&Ws[(nt*16 + li)*72 + ks*32 + grp*8];
      acc[nt] = __builtin_amdgcn_mfma_f32_16x16x32_bf16(a, b, acc[nt], 0, 0, 0);
    }
  }
  __syncthreads();   // all As/Ws reads complete

  // ---- write h; stage Wm_next; As <- bf16(h) ----
  stage_tile_bf16(Ws, Wm_next + (size_t)srow*80 + sc16, srow, sc16, true);
#pragma unroll
  for (int nt = 0; nt < 4; ++nt) {
    const int ch = nt*16 + li;
    const float b = bu[ch];
#pragma unroll
    for (int j = 0; j < 4; ++j) {
      const int row = wave*16 + grp*4 + j;
      const int gr = m0 + row;
      const float v = fmaxf(acc[nt][j] + b, 0.f);
      if (gr < M) Hout[(size_t)gr*ldh + ch] = v;
      As[row*72 + ch] = f2bf(v);               // wave-local rows
    }
  }
  __syncthreads();

  // ---- R GEMM ----
  f32x4 acc2[4];
#pragma unroll
  for (int nt = 0; nt < 4; ++nt) acc2[nt] = (f32x4)0.f;
#pragma unroll
  for (int ks = 0; ks < 2; ++ks) {
    const short8v a = *(const short8v*)&As[(wave*16 + li)*72 + ks*32 + grp*8];
#pragma unroll
    for (int nt = 0; nt < 4; ++nt) {
      const short8v b = *(const short8v*)&Ws[(nt*16 + li)*72 + ks*32 + grp*8];
      acc2[nt] = __builtin_amdgcn_mfma_f32_16x16x32_bf16(a, b, acc2[nt], 0, 0, 0);
    }
  }
#pragma unroll
  for (int nt = 0; nt < 4; ++nt) {
    const int ch = nt*16 + li;
#pragma unroll
    for (int j = 0; j < 4; ++j) {
      const int gr = m0 + wave*16 + grp*4 + j;
      if (gr < M) Rout[(size_t)gr*64 + ch] = acc2[nt][j];
    }
  }
}

// ---------------------------------------------------------------------------
// bf16-MFMA linear (round-14 version, verified).
// ---------------------------------------------------------------------------
template<bool RELU>
__global__ __launch_bounds__(256) void linear_kernel(
    const float* __restrict__ A, int lda,
    const float* __restrict__ W, int ldw,
    const float* __restrict__ bias,
    float* __restrict__ C, int ldc, int M, int K)
{
  __shared__ short As[64 * 72];
  __shared__ short Ws[64 * 72];
  const int tid = threadIdx.x;
  const int wave = tid >> 6, lane = tid & 63;
  const int grp = lane >> 4, li = lane & 15;
  const int m0 = blockIdx.x * 64;
  const int c0 = blockIdx.y * 64;

  f32x4 acc[4];
#pragma unroll
  for (int nt = 0; nt < 4; ++nt) acc[nt] = (f32x4)0.f;

  const int srow = tid >> 2;
  const int sc16 = (tid & 3) * 16;

  for (int kt = 0; kt < K; kt += 64) {
    const int gr = m0 + srow;
    stage_tile_bf16(As, A + (size_t)gr*lda + kt + sc16, srow, sc16, gr < M);
    stage_tile_bf16(Ws, W + (size_t)(c0 + srow)*ldw + kt + sc16, srow, sc16, true);
    __syncthreads();
#pragma unroll
    for (int ks = 0; ks < 2; ++ks) {
      const short8v a = *(const short8v*)&As[(wave*16 + li)*72 + ks*32 + grp*8];
#pragma unroll
      for (int nt = 0; nt < 4; ++nt) {
        const short8v b = *(const short8v*)&Ws[(nt*16 + li)*72 + ks*32 + grp*8];
        acc[nt] = __builtin_amdgcn_mfma_f32_16x16x32_bf16(a, b, acc[nt], 0, 0, 0);
      }
    }
    __syncthreads();
  }

#pragma unroll
  for (int nt = 0; nt < 4; ++nt) {
    const int ch = c0 + nt*16 + li;
    const float b = bias ? bias[ch] : 0.f;
#pragma unroll
    for (int j = 0; j < 4; ++j) {
      const int gr = m0 + wave*16 + grp*4 + j;
      if (gr < M) {
        float v = acc[nt][j] + b;
        if (RELU) v = fmaxf(v, 0.f);
        C[(size_t)gr*ldc + ch] = v;
      }
    }
  }
}

// ---------------------------------------------------------------------------
// Fused output stage: msg3 (into LDS) -> h3 tile (LDS) -> fu1 (LDS) ->
// out = [CAT,h3]@f2w[:,64:]^T + fu1@f2w[:,0:64]^T + f2b.
// ---------------------------------------------------------------------------
__global__ __launch_bounds__(256) void fusion_kernel(
    const float* __restrict__ CAT,
    const float* __restrict__ R3, const short* __restrict__ eac,
    const float* __restrict__ wm3, const float* __restrict__ bm3,
    const int* __restrict__ cs_src, const int* __restrict__ rowptr,
    const float* __restrict__ wu3, const float* __restrict__ bu3,
    const float* __restrict__ f1w, const float* __restrict__ f1b,
    const float* __restrict__ f2w, const float* __restrict__ f2bias,
    float* __restrict__ out, int M)
{
  __shared__ short As[64 * 72];
  __shared__ short W1s[64 * 72];
  __shared__ short W2s[64 * 72];
  __shared__ short H3s[64 * 72];
  const int tid = threadIdx.x;
  const int wave = tid >> 6, lane = tid & 63;
  const int grp = lane >> 4, li = lane & 15;
  const int m0 = blockIdx.x * 64;
  const int srow = tid >> 2;
  const int sc16 = (tid & 3) * 16;

  // ---- msg3 phase -> As (bf16 agg tile) ----
  {
    short8v bfr[4]; float bmv[4];
    msg_frags(wm3, bm3, bfr, bmv, grp, li);
    msg_phase(As, R3, eac, bfr, bmv, cs_src, rowptr, m0, wave, lane, grp, li, M);
  }

  // ---- phase 0: h3 tile ----
  stage_tile_bf16(W1s, wu3 + (size_t)srow*64 + sc16, srow, sc16, true);
  __syncthreads();
  f32x4 acc1[4], acc2[4];
#pragma unroll
  for (int nt = 0; nt < 4; ++nt) { acc1[nt] = (f32x4)0.f; acc2[nt] = (f32x4)0.f; }
#pragma unroll
  for (int ks = 0; ks < 2; ++ks) {
    const short8v a = *(const short8v*)&As[(wave*16 + li)*72 + ks*32 + grp*8];
#pragma unroll
    for (int nt = 0; nt < 4; ++nt) {
      const short8v b = *(const short8v*)&W1s[(nt*16 + li)*72 + ks*32 + grp*8];
      acc1[nt] = __builtin_amdgcn_mfma_f32_16x16x32_bf16(a, b, acc1[nt], 0, 0, 0);
    }
  }
#pragma unroll
  for (int nt = 0; nt < 4; ++nt) {
    const int ch = nt*16 + li;
    const float b = bu3[ch];
#pragma unroll
    for (int j = 0; j < 4; ++j) {
      const int row = wave*16 + grp*4 + j;
      H3s[row*72 + ch] = f2bf(fmaxf(acc1[nt][j] + b, 0.f));   // wave-local rows
    }
  }
  __syncthreads();

  // ---- main loop: 4 CAT tiles + h3 tile ----
#pragma unroll
  for (int nt = 0; nt < 4; ++nt) acc1[nt] = (f32x4)0.f;
  for (int tile = 0; tile < 5; ++tile) {
    const int kt = tile * 64;
    if (tile < 4) {
      const int gr = m0 + srow;
      stage_tile_bf16(As, CAT + (size_t)gr*320 + kt + sc16, srow, sc16, gr < M);
    }
    stage_tile_bf16(W1s, f1w + (size_t)srow*320 + kt + sc16, srow, sc16, true);
    stage_tile_bf16(W2s, f2w + (size_t)srow*384 + 64 + kt + sc16, srow, sc16, true);
    __syncthreads();
    const short* Ause = (tile < 4) ? As : H3s;
#pragma unroll
    for (int ks = 0; ks < 2; ++ks) {
      const short8v a = *(const short8v*)&Ause[(wave*16 + li)*72 + ks*32 + grp*8];
#pragma unroll
      for (int nt = 0; nt < 4; ++nt) {
        const short8v b1 = *(const short8v*)&W1s[(nt*16 + li)*72 + ks*32 + grp*8];
        const short8v b2 = *(const short8v*)&W2s[(nt*16 + li)*72 + ks*32 + grp*8];
        acc1[nt] = __builtin_amdgcn_mfma_f32_16x16x32_bf16(a, b1, acc1[nt], 0, 0, 0);
        acc2[nt] = __builtin_amdgcn_mfma_f32_16x16x32_bf16(a, b2, acc2[nt], 0, 0, 0);
      }
    }
    __syncthreads();
  }

  // ---- fu1 finish ----
  stage_tile_bf16(W1s, f2w + (size_t)srow*384 + sc16, srow, sc16, true);
#pragma unroll
  for (int nt = 0; nt < 4; ++nt) {
    const int ch = nt*16 + li;
    const float b = f1b[ch];
#pragma unroll
    for (int j = 0; j < 4; ++j) {
      const int row = wave*16 + grp*4 + j;
      As[row*72 + ch] = f2bf(fmaxf(acc1[nt][j] + b, 0.f));    // wave-local rows
    }
  }
  __syncthreads();
#pragma unroll
  for (int ks = 0; ks < 2; ++ks) {
    const short8v a = *(const short8v*)&As[(wave*16 + li)*72 + ks*32 + grp*8];
#pragma unroll
    for (int nt = 0; nt < 4; ++nt) {
      const short8v b = *(const short8v*)&W1s[(nt*16 + li)*72 + ks*32 + grp*8];
      acc2[nt] = __builtin_amdgcn_mfma_f32_16x16x32_bf16(a, b, acc2[nt], 0, 0, 0);
    }
  }
#pragma unroll
  for (int nt = 0; nt < 4; ++nt) {
    const int ch = nt*16 + li;
    const float b = f2bias[ch];
#pragma unroll
    for (int j = 0; j < 4; ++j) {
      const int gr = m0 + wave*16 + grp*4 + j;
      if (gr < M) out[(size_t)gr*64 + ch] = acc2[nt][j] + b;
    }
  }
}

// ---------------------------------------------------------------------------
// Dynamic conv via MFMA (bf16), unchanged.
// ---------------------------------------------------------------------------
#define TPW 4   // targets per wave

__global__ __launch_bounds__(256) void dyn_mfma_kernel(
    const float* __restrict__ PQ,
    const float* __restrict__ W2, const float* __restrict__ b2,
    const int* __restrict__ knn, float* __restrict__ out, int ldo, int n)
{
  __shared__ short w2s[64 * 136];
  __shared__ short Ts[4][17 * 136];
  const int tid = threadIdx.x;
  const int wave = tid >> 6, lane = tid & 63;

  for (int idx = tid; idx < 64 * 128; idx += 256) {
    const int c = idx >> 7, k = idx & 127;
    w2s[c*136 + k] = f2bf(W2[c*128 + k]);
  }
  __syncthreads();

  short8v bfr[4][4];
#pragma unroll
  for (int nt = 0; nt < 4; ++nt)
#pragma unroll
    for (int kt = 0; kt < 4; ++kt)
      bfr[nt][kt] = *(const short8v*)&w2s[(nt*16 + (lane&15))*136 +
                                          kt*32 + (lane>>4)*8];
  const float b2v = b2[lane];
  short* T = Ts[wave];

  for (int tg = 0; tg < TPW; ++tg) {
    const int i = (blockIdx.x * 4 + wave) * TPW + tg;
    if (i >= n) break;
    const size_t i16 = (size_t)i * 16;

    for (int s = 0; s < 9; ++s) {
      const int slot = lane + 64*s;
      if (slot < 544) {
        const int row = slot >> 5, k4 = slot & 31;
        const int j = (row < 16) ? knn[i16 + row] : i;
        const float4 p = *(const float4*)(PQ + (size_t)i*256 + k4*4);
        const float4 q = *(const float4*)(PQ + (size_t)j*256 + 128 + k4*4);
        const float t0 = fmaxf(p.x + q.x, 0.f), t1 = fmaxf(p.y + q.y, 0.f);
        const float t2 = fmaxf(p.z + q.z, 0.f), t3 = fmaxf(p.w + q.w, 0.f);
        int2 w;
        w.x = ((int)(unsigned short)f2bf(t1) << 16) | (unsigned short)f2bf(t0);
        w.y = ((int)(unsigned short)f2bf(t3) << 16) | (unsigned short)f2bf(t2);
        *(int2*)&T[row*136 + k4*4] = w;
      }
    }

    f32x4 acc0[4], acc1[4];
#pragma unroll
    for (int nt = 0; nt < 4; ++nt) {
      acc0[nt] = (f32x4)0.f;
      acc1[nt] = (f32x4)0.f;
    }
#pragma unroll
    for (int kt = 0; kt < 4; ++kt) {
      const short8v a1 = *(const short8v*)&T[(lane&15)*136 + kt*32 + (lane>>4)*8];
      const short8v a2 = *(const short8v*)&T[16*136 + kt*32 + (lane>>4)*8];
#pragma unroll
      for (int nt = 0; nt < 4; ++nt) {
        acc0[nt] = __builtin_amdgcn_mfma_f32_16x16x32_bf16(a1, bfr[nt][kt], acc0[nt], 0, 0, 0);
        acc1[nt] = __builtin_amdgcn_mfma_f32_16x16x32_bf16(a2, bfr[nt][kt], acc1[nt], 0, 0, 0);
      }
    }

    float v[4];
#pragma unroll
    for (int nt = 0; nt < 4; ++nt) {
      float m = fmaxf(fmaxf(acc0[nt][0], acc0[nt][1]),
                      fmaxf(acc0[nt][2], acc0[nt][3]));
      m = fmaxf(m, acc1[nt][0]);
      m = fmaxf(m, __shfl_xor(m, 16, 64));
      m = fmaxf(m, __shfl_xor(m, 32, 64));
      v[nt] = m;
    }
    const int g = lane >> 4;
    float r = v[0];
    r = (g == 1) ? v[1] : r;
    r = (g == 2) ? v[2] : r;
    r = (g == 3) ? v[3] : r;
    out[(size_t)i*ldo + lane] = fmaxf(r + b2v, 0.f);
  }
}

// ---------------------------------------------------------------------------
// Host orchestration
// ---------------------------------------------------------------------------
extern "C" void kernel_launch(void* const* d_in, const int* in_sizes, int n_in,
                              void* d_out, int out_size, void* d_ws, size_t ws_size,
                              hipStream_t stream)
{
  const float* x   = (const float*)d_in[0];
  const int*   ei  = (const int*)d_in[1];
  const float* ea  = (const float*)d_in[2];
  const float* loc = (const float*)d_in[3];
  const float* sg_wm[3] = {(const float*)d_in[5],  (const float*)d_in[9],  (const float*)d_in[13]};
  const float* sg_bm[3] = {(const float*)d_in[6],  (const float*)d_in[10], (const float*)d_in[14]};
  const float* sg_wu[3] = {(const float*)d_in[7],  (const float*)d_in[11], (const float*)d_in[15]};
  const float* sg_bu[3] = {(const float*)d_in[8],  (const float*)d_in[12], (const float*)d_in[16]};
  const float* dg_w1[2] = {(const float*)d_in[17], (const float*)d_in[21]};
  const float* dg_b1[2] = {(const float*)d_in[18], (const float*)d_in[22]};
  const float* dg_w2[2] = {(const float*)d_in[19], (const float*)d_in[23]};
  const float* dg_b2[2] = {(const float*)d_in[20], (const float*)d_in[24]};
  const float* f1_w = (const float*)d_in[25];
  const float* f1_b = (const float*)d_in[26];
  const float* f2_w = (const float*)d_in[27];
  const float* f2_b = (const float*)d_in[28];
  float* out = (float*)d_out;

  const int n    = in_sizes[0] / 64;
  const int Etot = in_sizes[1] / 2;
  const int* srcp = ei;
  const int* dstp = ei + Etot;

  char* basep = (char*)d_ws;
  size_t cur = 0;
  auto alloc = [&](size_t bytes) -> void* {
    void* p = basep + cur;
    cur = (cur + bytes + 255) & ~(size_t)255;
    return p;
  };
  float* CAT  = (float*)alloc((size_t)n * 320 * 4);   // cols 256.. unused
  float* Rb   = (float*)alloc((size_t)n * 64 * 4);
  float* Rb2  = (float*)alloc((size_t)n * 64 * 4);
  float* PQb  = (float*)alloc((size_t)n * 256 * 4);
  float* wpq[2];
  float* bpq[2];
  wpq[0] = (float*)alloc(256 * 64 * 4);  bpq[0] = (float*)alloc(256 * 4);
  wpq[1] = (float*)alloc(256 * 64 * 4);  bpq[1] = (float*)alloc(256 * 4);
  int* knnb   = (int*)alloc((size_t)n * 16 * 4);
  int* zeros     = (int*)alloc((size_t)(2*KNN_NC + 2*n) * 4);
  int* cellcount = zeros;
  int* cellfill  = zeros + KNN_NC;
  int* deg       = zeros + 2*KNN_NC;
  int* dfill     = zeros + 2*KNN_NC + n;
  int* cellstart = (int*)alloc((size_t)(KNN_NC + 1) * 4);
  int* cellidb   = (int*)alloc((size_t)n * 4);
  float* locs4s  = (float*)alloc((size_t)n * 4 * 4);
  int* oidx      = (int*)alloc((size_t)n * 4);
  int* rowptr    = (int*)alloc((size_t)(n + 1) * 4);
  int* cs_src    = (int*)alloc((size_t)Etot * 4);
  int* cs_eid    = (int*)alloc((size_t)Etot * 4);
  short* ea_csr  = (short*)alloc((size_t)Etot * 16 * 2);   // bf16
  (void)ws_size; (void)n_in; (void)out_size;

  const int nbE = (Etot + 255) / 256;
  const int mb = (n + 63) / 64;

  hipMemsetAsync(zeros, 0, (size_t)(2*KNN_NC + 2*n) * 4, stream);
  count2_kernel<<<nbE, 256, 0, stream>>>(loc, cellcount, cellidb, n,
                                         dstp, deg, Etot);
  scan2_kernel<<<2, 1024, 0, stream>>>(cellcount, cellstart, KNN_NC,
                                       (KNN_NC + 1023) / 1024,
                                       deg, rowptr, n, (n + 1023) / 1024);
  scatter2_kernel<<<nbE, 256, 0, stream>>>(loc, cellidb, cellstart, cellfill,
                                           locs4s, oidx, n,
                                           srcp, dstp, rowptr, dfill,
                                           cs_src, cs_eid, Etot);
  const int KB = (n + 3) / 4;
  const int EB = (Etot + 255) / 256;      // one edge per thread
  mega_kernel<<<KB + EB + 64 + mb, 256, 0, stream>>>(
      locs4s, oidx, cellstart, knnb, n,
      ea, cs_eid, ea_csr, Etot,
      dg_w1[0], dg_b1[0], wpq[0], bpq[0],
      dg_w1[1], dg_b1[1], wpq[1], bpq[1],
      x, sg_wm[0] + 16, Rb,
      KB, EB);

  auto lin = [&](const float* A, int lda, const float* W, int ldw, const float* bias,
                 float* C, int ldc, int K, int ncols, bool relu) {
    dim3 grid(mb, ncols / 64);
    if (relu) linear_kernel<true ><<<grid, 256, 0, stream>>>(A, lda, W, ldw, bias, C, ldc, n, K);
    else      linear_kernel<false><<<grid, 256, 0, stream>>>(A, lda, W, ldw, bias, C, ldc, n, K);
  };

  // static layers (fully fused): R1 -> [msg1+h1+R2] -> [msg2+h2+R3] -> fusion(msg3+h3)
  static_layer_kernel<<<mb, 256, 0, stream>>>(
      Rb, ea_csr, sg_wm[0], sg_bm[0], cs_src, rowptr,
      sg_wu[0], sg_bu[0], CAT + 0, 320, sg_wm[1] + 16, Rb2, n);   // h1, R2
  static_layer_kernel<<<mb, 256, 0, stream>>>(
      Rb2, ea_csr, sg_wm[1], sg_bm[1], cs_src, rowptr,
      sg_wu[1], sg_bu[1], CAT + 192, 320, sg_wm[2] + 16, Rb, n);  // h2, R3

  // dynamic layers: h1 -> g1(CAT+64); g1 -> g2(CAT+128)
  const float* din[2] = {CAT + 0, CAT + 64};
  float* doutp[2] = {CAT + 64, CAT + 128};
  const int db = (n + 4*TPW - 1) / (4*TPW);
  for (int l = 0; l < 2; ++l) {
    lin(din[l], 320, wpq[l], 64, bpq[l], PQb, 256, 64, 256, false);
    dyn_mfma_kernel<<<db, 256, 0, stream>>>(PQb, dg_w2[l], dg_b2[l],
                                            knnb, doutp[l], 320, n);
  }

  // fused output stage (msg3 + h3 + fu1 + out)
  fusion_kernel<<<mb, 256, 0, stream>>>(
      CAT, Rb, ea_csr, sg_wm[2], sg_bm[2], cs_src, rowptr,
      sg_wu[2], sg_bu[2], f1_w, f1_b, f2_w, f2_b, out, n);
}

// Round 19
// 295.478 us; speedup vs baseline: 1.6911x; 1.6911x over previous
//
#include <hip/hip_runtime.h>

#define INF_F __builtin_inff()

typedef __attribute__((ext_vector_type(8))) short short8v;  // 8 bf16
typedef __attribute__((ext_vector_type(4))) float f32x4;
typedef unsigned long long ull;

__device__ __forceinline__ short f2bf(float x) {
  const unsigned u = __float_as_uint(x);
  return (short)((u + 0x7FFFu + ((u >> 16) & 1u)) >> 16);   // RNE
}

__device__ __forceinline__ unsigned mbcnt64(ull m) {
  return __builtin_amdgcn_mbcnt_hi((unsigned)(m >> 32),
                                   __builtin_amdgcn_mbcnt_lo((unsigned)m, 0u));
}

// ===========================================================================
// Spatial-bin exact kNN, WAVE-per-target, G=5, materialized flat positions,
// per-target face bound for escalation (round-13..17 config, measured ~73 us).
// ===========================================================================
#define KNN_G 5
#define KNN_NC (KNN_G*KNN_G*KNN_G*KNN_G)   // 625
#define KNN_PCAP 1600

// ---- merged init kernels ---------------------------------------------------
__global__ __launch_bounds__(256) void count2_kernel(
    const float* __restrict__ loc, int* __restrict__ cellcount,
    int* __restrict__ cellid, int n,
    const int* __restrict__ dst, int* __restrict__ deg, int E)
{
  const int i = blockIdx.x * 256 + threadIdx.x;
  if (i < n) {
    const float4 l = *(const float4*)(loc + (size_t)i*4);
    const int cx = min(KNN_G-1, (int)(l.x * (float)KNN_G));
    const int cy = min(KNN_G-1, (int)(l.y * (float)KNN_G));
    const int cz = min(KNN_G-1, (int)(l.z * (float)KNN_G));
    const int cw = min(KNN_G-1, (int)(l.w * (float)KNN_G));
    const int c = ((cx*KNN_G + cy)*KNN_G + cz)*KNN_G + cw;
    cellid[i] = c;
    atomicAdd(&cellcount[c], 1);
  }
  if (i < E) atomicAdd(&deg[dst[i]], 1);
}

__device__ __forceinline__ void scan1b_body(
    const int* __restrict__ in, int* __restrict__ out, int n, int per)
{
  __shared__ int part[1024];
  const int t = threadIdx.x;
  const int lo = t * per, hi = min(lo + per, n);
  int sum = 0;
  for (int idx = lo; idx < hi; ++idx) sum += in[idx];
  int v = sum;
  part[t] = v;
  __syncthreads();
  for (int off = 1; off < 1024; off <<= 1) {
    const int o = (t >= off) ? part[t - off] : 0;
    __syncthreads();
    v += o;
    part[t] = v;
    __syncthreads();
  }
  int run = v - sum;
  for (int idx = lo; idx < hi; ++idx) { out[idx] = run; run += in[idx]; }
  if (t == 1023) out[n] = v;
}

__global__ __launch_bounds__(1024) void scan2_kernel(
    const int* __restrict__ inA, int* __restrict__ outA, int nA, int perA,
    const int* __restrict__ inB, int* __restrict__ outB, int nB, int perB)
{
  if (blockIdx.x == 0) scan1b_body(inA, outA, nA, perA);
  else                 scan1b_body(inB, outB, nB, perB);
}

__global__ __launch_bounds__(256) void scatter2_kernel(
    const float* __restrict__ loc, const int* __restrict__ cellid,
    const int* __restrict__ cellstart, int* __restrict__ cellfill,
    float* __restrict__ locs4s, int* __restrict__ oidx, int n,
    const int* __restrict__ srcs, const int* __restrict__ dsts,
    const int* __restrict__ rowptr, int* __restrict__ dfill,
    int* __restrict__ cs_src, int* __restrict__ cs_eid, int E)
{
  const int i = blockIdx.x * 256 + threadIdx.x;
  if (i < n) {
    const int c = cellid[i];
    const int pos = cellstart[c] + atomicAdd(&cellfill[c], 1);
    *(float4*)(locs4s + (size_t)pos*4) = *(const float4*)(loc + (size_t)i*4);
    oidx[pos] = i;
  }
  if (i < E) {
    const int d = dsts[i];
    const int pos = rowptr[d] + atomicAdd(&dfill[d], 1);
    cs_src[pos] = srcs[i];
    cs_eid[pos] = i;
  }
}

// ---- kNN selection helpers -------------------------------------------------
__device__ __forceinline__ ull
knn_refine16(ull* __restrict__ B, int cnt, int lane, ull& topsave)
{
  ull v[5];
#pragma unroll
  for (int s = 0; s < 5; ++s) {
    const int idx = lane + 64*s;
    v[s] = (idx < cnt) ? B[idx] : ~0ull;
  }
  ull tau = ~0ull;
#pragma unroll
  for (int r = 0; r < 16; ++r) {
    ull m = v[0]; int sl = 0;
#pragma unroll
    for (int s = 1; s < 5; ++s) if (v[s] < m) { m = v[s]; sl = s; }
    ull mm = m;
#pragma unroll
    for (int off = 32; off >= 1; off >>= 1) {
      const ull o = __shfl_xor(mm, off, 64);
      if (o < mm) mm = o;
    }
    const bool killer = (m == mm);
#pragma unroll
    for (int s = 0; s < 5; ++s) if (killer && sl == s) v[s] = ~0ull;
    if (lane == r) topsave = mm;
    tau = mm;            // after round 15: exact 16th-smallest
  }
  if (lane < 16) B[lane] = topsave;
  return tau;
}

__device__ __forceinline__ int
knn_filter(ull* __restrict__ B, int cnt, int lane, ull& tau)
{
  ull v[5];
#pragma unroll
  for (int s = 0; s < 5; ++s) {
    const int idx = lane + 64*s;
    v[s] = (idx < cnt) ? B[idx] : ~0ull;
  }
  ull g = v[0];
#pragma unroll
  for (int s = 1; s < 5; ++s) if (v[s] < g) g = v[s];
  { ull o = __shfl_xor(g, 1, 64); if (o < g) g = o;
    o = __shfl_xor(g, 2, 64); if (o < g) g = o; }
  ull t = g;
#pragma unroll
  for (int off = 4; off <= 32; off <<= 1) {
    const ull o = __shfl_xor(t, off, 64);
    if (o > t) t = o;
  }
  int nc = 0;
#pragma unroll
  for (int s = 0; s < 5; ++s) {
    const bool keep = (v[s] <= t) && (v[s] != ~0ull);
    const ull mask = __ballot(keep);
    if (mask) {
      const unsigned pre = mbcnt64(mask);
      if (keep) B[nc + pre] = v[s];
      nc += (int)__popcll(mask);
    }
  }
  tau = t;
  return nc;
}

__device__ void knn_body(int blk, ull* __restrict__ Bs, int* __restrict__ PosAll,
                         const float* __restrict__ locs4s,
                         const int* __restrict__ oidx,
                         const int* __restrict__ cellstart,
                         int* __restrict__ knn, int n)
{
#pragma clang fp contract(off)
  constexpr int TRIG = 256;
  const int wave = threadIdx.x >> 6, lane = threadIdx.x & 63;
  const int t = blk * 4 + wave;          // sorted position of target
  if (t >= n) return;                    // wave-uniform exit
  ull* B = Bs + wave * 320;
  int* Pos = PosAll + wave * KNN_PCAP;

  const float4 L = *(const float4*)(locs4s + (size_t)t*4);
  const float tx = L.x, ty = L.y, tz = L.z, tw = L.w;
  const int cx = min(KNN_G-1, (int)(tx * (float)KNN_G));
  const int cy = min(KNN_G-1, (int)(ty * (float)KNN_G));
  const int cz = min(KNN_G-1, (int)(tz * (float)KNN_G));
  const int cw = min(KNN_G-1, (int)(tw * (float)KNN_G));

  ull tau = ~0ull;
  ull topsave = ~0ull;
  int cnt = 0;

  auto boundB = [&](int mr) -> float {
    const float w = 1.0f / (float)KNN_G;
    float Bv = INF_F;
    if (cx - mr >= 1)         Bv = fminf(Bv, tx - (float)(cx - mr) * w);
    if (cx + mr <= KNN_G - 2) Bv = fminf(Bv, (float)(cx + mr + 1) * w - tx);
    if (cy - mr >= 1)         Bv = fminf(Bv, ty - (float)(cy - mr) * w);
    if (cy + mr <= KNN_G - 2) Bv = fminf(Bv, (float)(cy + mr + 1) * w - ty);
    if (cz - mr >= 1)         Bv = fminf(Bv, tz - (float)(cz - mr) * w);
    if (cz + mr <= KNN_G - 2) Bv = fminf(Bv, (float)(cz + mr + 1) * w - tz);
    if (cw - mr >= 1)         Bv = fminf(Bv, tw - (float)(cw - mr) * w);
    if (cw + mr <= KNN_G - 2) Bv = fminf(Bv, (float)(cw + mr + 1) * w - tw);
    return Bv;
  };

  auto do_range = [&](int ps, int pe) {
    for (int p0 = ps; p0 < pe; p0 += 64) {
      const int p = p0 + lane;
      ull key = ~0ull;
      if (p < pe && p != t) {
        const float4 q = *(const float4*)(locs4s + (size_t)p*4);
        const int oj = oidx[p];
        const float a0 = q.x - tx, a1 = q.y - ty, a2 = q.z - tz, a3 = q.w - tw;
        const float s0 = a0*a0, s1 = a1*a1, s2 = a2*a2, s3 = a3*a3;
        const float d = ((s0 + s1) + s2) + s3;
        key = ((ull)__float_as_uint(d) << 32) | (unsigned)oj;
      }
      const bool surv = key < tau;
      const ull mask = __ballot(surv);
      if (mask) {
        const unsigned pre = mbcnt64(mask);
        if (surv) B[cnt + pre] = key;
        cnt += (int)__popcll(mask);
        if (cnt > TRIG) cnt = knn_filter(B, cnt, lane, tau);
      }
    }
  };

  // ---- level 0: radius-1 block as a materialized flat position list ----
  int psv = 0, pev = 0;
  if (lane < 27) {
    const int cr = (lane == 0) ? 13 : (lane <= 13 ? lane - 1 : lane);
    const int ax = cx + (cr / 9) - 1;
    const int ay = cy + ((cr / 3) % 3) - 1;
    const int az = cz + (cr % 3) - 1;
    if (ax >= 0 && ax < KNN_G && ay >= 0 && ay < KNN_G &&
        az >= 0 && az < KNN_G) {
      const int base = ((ax*KNN_G + ay)*KNN_G + az)*KNN_G;
      const int wlo = max(cw-1, 0), whi = min(cw+1, KNN_G-1);
      psv = cellstart[base + wlo];
      pev = cellstart[base + whi + 1];
    }
  }
  const int len = max(pev - psv, 0);
  int cum = len;
#pragma unroll
  for (int off = 1; off < 64; off <<= 1) {
    const int o = __shfl_up(cum, off, 64);
    if (lane >= off) cum += o;
  }
  const int T = __shfl(cum, 63, 64);
  const int startv = cum - len;

  for (int p = psv, f = startv; p < pev && f < KNN_PCAP; ++p, ++f) Pos[f] = p;

  const int Tb = min(T, KNN_PCAP);
  const int Tm1b = Tb - 1;
  float4 qn; int ojn = 0, pgn = 0; bool vn = false;
  {
    vn = lane < Tb;
    pgn = Pos[min(lane, Tm1b)];
    qn = *(const float4*)(locs4s + (size_t)pgn*4);
    ojn = oidx[pgn];
  }
  for (int f0 = 0; f0 < Tb; f0 += 64) {
    const float4 qc = qn; const int ojc = ojn, pgc = pgn; const bool vc = vn;
    const int fN = f0 + 64 + lane;
    vn = fN < Tb;
    if (f0 + 64 < Tb) {
      pgn = Pos[min(fN, Tm1b)];
      qn = *(const float4*)(locs4s + (size_t)pgn*4);
      ojn = oidx[pgn];
    }
    ull key = ~0ull;
    if (vc && pgc != t) {
      const float a0 = qc.x - tx, a1 = qc.y - ty, a2 = qc.z - tz, a3 = qc.w - tw;
      const float s0 = a0*a0, s1 = a1*a1, s2 = a2*a2, s3 = a3*a3;
      const float d = ((s0 + s1) + s2) + s3;
      key = ((ull)__float_as_uint(d) << 32) | (unsigned)ojc;
    }
    const bool surv = key < tau;
    const ull mask = __ballot(surv);
    if (mask) {
      const unsigned pre = mbcnt64(mask);
      if (surv) B[cnt + pre] = key;
      cnt += (int)__popcll(mask);
      if (cnt > TRIG) cnt = knn_filter(B, cnt, lane, tau);
    }
  }
  if (T > KNN_PCAP) {
    for (int r = 0; r < 27; ++r) {
      const int st = __shfl(startv, r, 64);
      const int ps = __shfl(psv, r, 64);
      const int pe = __shfl(pev, r, 64);
      const int done = min(max(KNN_PCAP - st, 0), pe - ps);
      if (ps + done < pe) do_range(ps + done, pe);
    }
  }

  // ---- shells m = 2..G-1 (rare; exact refine + per-target bound check) ----
  for (int m = 2; m <= KNN_G - 1; ++m) {
    if (cnt > 16) { tau = knn_refine16(B, cnt, lane, topsave); cnt = 16; }
    if (tau != ~0ull) {
      const float taud = __uint_as_float((unsigned)(tau >> 32));
      const float Bv = boundB(m - 1);
      if (Bv == INF_F || taud < Bv * Bv * 0.99999f) break;
    }
    const int xlo = max(cx-m, 0), xhi = min(cx+m, KNN_G-1);
    for (int ax = xlo; ax <= xhi; ++ax) {
      const bool xe = (ax == cx-m) || (ax == cx+m);
      const int ylo = max(cy-m, 0), yhi = min(cy+m, KNN_G-1);
      for (int ay = ylo; ay <= yhi; ++ay) {
        const bool ye = (ay == cy-m) || (ay == cy+m);
        const int zlo = max(cz-m, 0), zhi = min(cz+m, KNN_G-1);
        for (int az = zlo; az <= zhi; ++az) {
          const bool ze = (az == cz-m) || (az == cz+m);
          const int base = ((ax*KNN_G + ay)*KNN_G + az)*KNN_G;
          if (xe | ye | ze) {
            const int wlo = max(cw-m, 0), whi = min(cw+m, KNN_G-1);
            do_range(cellstart[base+wlo], cellstart[base+whi+1]);
          } else {
            if (cw-m >= 0) {
              const int c = base + cw - m;
              do_range(cellstart[c], cellstart[c+1]);
            }
            if (cw+m <= KNN_G-1) {
              const int c = base + cw + m;
              do_range(cellstart[c], cellstart[c+1]);
            }
          }
        }
      }
    }
  }
  (void)knn_refine16(B, cnt, lane, topsave);   // exact top-16
  const int i = oidx[t];
  if (lane < 16) knn[(size_t)i*16 + lane] = (int)(topsave & 0xFFFFFFFFull);
}

// ---------------------------------------------------------------------------
// Staging helper: convert a 64x64 fp32 tile row-chunk to bf16 LDS (pitch 72).
// ---------------------------------------------------------------------------
__device__ __forceinline__ void stage_tile_bf16(
    short* __restrict__ S, const float* __restrict__ src, int srow, int sc16,
    bool valid)
{
  short tmp[16];
  if (valid) {
#pragma unroll
    for (int u = 0; u < 4; ++u) {
      const float4 v = *(const float4*)(src + u*4);
      tmp[u*4+0] = f2bf(v.x); tmp[u*4+1] = f2bf(v.y);
      tmp[u*4+2] = f2bf(v.z); tmp[u*4+3] = f2bf(v.w);
    }
  } else {
#pragma unroll
    for (int u = 0; u < 16; ++u) tmp[u] = 0;
  }
  *(short8v*)&S[srow*72 + sc16]     = *(short8v*)&tmp[0];
  *(short8v*)&S[srow*72 + sc16 + 8] = *(short8v*)&tmp[8];
}

// ---------------------------------------------------------------------------
// Mega kernel: [0,KB) knn | [KB,KB+EB) ea permute->bf16 | [KB+EB,+64) pack |
// [KB+EB+64, +MB) R1 = x @ wm1[:,16:]^T  (bf16 MFMA).
// ---------------------------------------------------------------------------
__global__ __launch_bounds__(256) void mega_kernel(
    const float* __restrict__ locs4s, const int* __restrict__ oidx,
    const int* __restrict__ cellstart, int* __restrict__ knn, int n,
    const float* __restrict__ ea, const int* __restrict__ cs_eid,
    short* __restrict__ eac, int E,
    const float* __restrict__ w1A, const float* __restrict__ b1A,
    float* __restrict__ wpqA, float* __restrict__ bpqA,
    const float* __restrict__ w1B, const float* __restrict__ b1B,
    float* __restrict__ wpqB, float* __restrict__ bpqB,
    const float* __restrict__ x, const float* __restrict__ wm1,
    float* __restrict__ Rout,
    int KB, int EB)
{
  __shared__ __align__(16) char smem[4*320*8 + 4*KNN_PCAP*4];  // 35840 B
  const int bid = blockIdx.x;
  if (bid < KB) {
    knn_body(bid, (ull*)smem, (int*)(smem + 4*320*8),
             locs4s, oidx, cellstart, knn, n);
  } else if (bid < KB + EB) {
    const int e = (bid - KB) * 256 + threadIdx.x;
    if (e < E) {
      const float* src = ea + (size_t)cs_eid[e]*16;
      short tmp[16];
#pragma unroll
      for (int u = 0; u < 4; ++u) {
        const float4 v = *(const float4*)(src + u*4);
        tmp[u*4+0] = f2bf(v.x); tmp[u*4+1] = f2bf(v.y);
        tmp[u*4+2] = f2bf(v.z); tmp[u*4+3] = f2bf(v.w);
      }
      *(short8v*)(eac + (size_t)e*16)     = *(short8v*)&tmp[0];
      *(short8v*)(eac + (size_t)e*16 + 8) = *(short8v*)&tmp[8];
    }
  } else if (bid < KB + EB + 64) {
    const int gidx = (bid - KB - EB) * 256 + threadIdx.x;
    const int l = gidx >> 13;
    const int idx = gidx & 8191;
    const float* w1 = l ? w1B : w1A;
    const float* b1 = l ? b1B : b1A;
    float* wpq = l ? wpqB : wpqA;
    float* bpq = l ? bpqB : bpqA;
    const int o = idx >> 6, i = idx & 63;
    const float a = w1[o*128 + i], b = w1[o*128 + 64 + i];
    wpq[idx] = a - b;
    wpq[128*64 + idx] = b;
    if (idx < 128) { bpq[idx] = b1[idx]; bpq[128 + idx] = 0.f; }
  } else {
    // R1 GEMM: Rout = x @ wm1^T  (wm1 pre-offset +16, ld 80)
    short* As = (short*)smem;
    short* Ws = (short*)(smem + 64*72*2);
    const int tid = threadIdx.x;
    const int wave = tid >> 6, lane = tid & 63;
    const int grp = lane >> 4, li = lane & 15;
    const int m0 = (bid - KB - EB - 64) * 64;
    const int srow = tid >> 2;
    const int sc16 = (tid & 3) * 16;
    const int gr = m0 + srow;
    stage_tile_bf16(As, x + (size_t)gr*64 + sc16, srow, sc16, gr < n);
    stage_tile_bf16(Ws, wm1 + (size_t)srow*80 + sc16, srow, sc16, true);
    __syncthreads();
    f32x4 acc[4];
#pragma unroll
    for (int nt = 0; nt < 4; ++nt) acc[nt] = (f32x4)0.f;
#pragma unroll
    for (int ks = 0; ks < 2; ++ks) {
      const short8v a = *(const short8v*)&As[(wave*16 + li)*72 + ks*32 + grp*8];
#pragma unroll
      for (int nt = 0; nt < 4; ++nt) {
        const short8v b = *(const short8v*)&Ws[(nt*16 + li)*72 + ks*32 + grp*8];
        acc[nt] = __builtin_amdgcn_mfma_f32_16x16x32_bf16(a, b, acc[nt], 0, 0, 0);
      }
    }
#pragma unroll
    for (int nt = 0; nt < 4; ++nt) {
      const int ch = nt*16 + li;
#pragma unroll
      for (int j = 0; j < 4; ++j) {
        const int r = m0 + wave*16 + grp*4 + j;
        if (r < n) Rout[(size_t)r*64 + ch] = acc[nt][j];
      }
    }
  }
}

// ---------------------------------------------------------------------------
// Static conv message + segment max via MFMA; 2 dsts per wave; ea in bf16
// (A-fragment is a direct 16-B load, no conversion).
// ---------------------------------------------------------------------------
#define TPW_S 2

__global__ __launch_bounds__(256) void static_msg_kernel(
    const float* __restrict__ R, const short* __restrict__ eac,
    const float* __restrict__ wm, const float* __restrict__ bm,
    const int* __restrict__ cs_src, const int* __restrict__ rowptr,
    float* __restrict__ agg, int n)
{
  const int wave = threadIdx.x >> 6, lane = threadIdx.x & 63;
  const int grp = lane >> 4, li = lane & 15;

  short8v bfr[4];
  float bmv[4];
#pragma unroll
  for (int nt = 0; nt < 4; ++nt) {
    short8v b = (short8v)0;
    if (grp < 2) {
      const int ch = nt*16 + li;
#pragma unroll
      for (int j = 0; j < 8; ++j) b[j] = f2bf(wm[ch*80 + grp*8 + j]);
    }
    bfr[nt] = b;
    bmv[nt] = bm[nt*16 + li];
  }
  const f32x4 zero = (f32x4)0.f;

  for (int tg = 0; tg < TPW_S; ++tg) {
    const int d = (blockIdx.x * 4 + wave) * TPW_S + tg;
    if (d >= n) break;                        // wave-uniform
    const int beg = rowptr[d], end = rowptr[d+1];
    const int deg = end - beg;
    float basev[4];
#pragma unroll
    for (int nt = 0; nt < 4; ++nt)
      basev[nt] = bmv[nt] - R[(size_t)d*64 + nt*16 + li];

    float vmax[4] = {0.f, 0.f, 0.f, 0.f};
    for (int m0 = 0; m0 < deg; m0 += 16) {
      short8v a = (short8v)0;
      const int erow = m0 + li;
      if (grp < 2 && erow < deg)
        a = *(const short8v*)(eac + (size_t)(beg + erow)*16 + grp*8);
      f32x4 Dv[4];
#pragma unroll
      for (int nt = 0; nt < 4; ++nt)
        Dv[nt] = __builtin_amdgcn_mfma_f32_16x16x32_bf16(a, bfr[nt], zero, 0, 0, 0);
#pragma unroll
      for (int j = 0; j < 4; ++j) {
        const int m = m0 + grp*4 + j;
        if (m < deg) {
          const int s = cs_src[beg + m];
          const float* Rs = R + (size_t)s*64;
#pragma unroll
          for (int nt = 0; nt < 4; ++nt) {
            const float acc = Dv[nt][j] + Rs[nt*16 + li] + basev[nt];
            vmax[nt] = fmaxf(vmax[nt], fmaxf(acc, 0.f));
          }
        }
      }
    }
#pragma unroll
    for (int nt = 0; nt < 4; ++nt) {
      float m = vmax[nt];
      m = fmaxf(m, __shfl_xor(m, 16, 64));
      m = fmaxf(m, __shfl_xor(m, 32, 64));
      vmax[nt] = m;
    }
    float r = vmax[0];
    r = (grp == 1) ? vmax[1] : r;
    r = (grp == 2) ? vmax[2] : r;
    r = (grp == 3) ? vmax[3] : r;
    agg[(size_t)d*64 + lane] = r;
  }
}

// ---------------------------------------------------------------------------
// bf16-MFMA linear (round-14 version, verified).
// ---------------------------------------------------------------------------
template<bool RELU>
__global__ __launch_bounds__(256) void linear_kernel(
    const float* __restrict__ A, int lda,
    const float* __restrict__ W, int ldw,
    const float* __restrict__ bias,
    float* __restrict__ C, int ldc, int M, int K)
{
  __shared__ short As[64 * 72];
  __shared__ short Ws[64 * 72];
  const int tid = threadIdx.x;
  const int wave = tid >> 6, lane = tid & 63;
  const int grp = lane >> 4, li = lane & 15;
  const int m0 = blockIdx.x * 64;
  const int c0 = blockIdx.y * 64;

  f32x4 acc[4];
#pragma unroll
  for (int nt = 0; nt < 4; ++nt) acc[nt] = (f32x4)0.f;

  const int srow = tid >> 2;
  const int sc16 = (tid & 3) * 16;

  for (int kt = 0; kt < K; kt += 64) {
    const int gr = m0 + srow;
    stage_tile_bf16(As, A + (size_t)gr*lda + kt + sc16, srow, sc16, gr < M);
    stage_tile_bf16(Ws, W + (size_t)(c0 + srow)*ldw + kt + sc16, srow, sc16, true);
    __syncthreads();
#pragma unroll
    for (int ks = 0; ks < 2; ++ks) {
      const short8v a = *(const short8v*)&As[(wave*16 + li)*72 + ks*32 + grp*8];
#pragma unroll
      for (int nt = 0; nt < 4; ++nt) {
        const short8v b = *(const short8v*)&Ws[(nt*16 + li)*72 + ks*32 + grp*8];
        acc[nt] = __builtin_amdgcn_mfma_f32_16x16x32_bf16(a, b, acc[nt], 0, 0, 0);
      }
    }
    __syncthreads();
  }

#pragma unroll
  for (int nt = 0; nt < 4; ++nt) {
    const int ch = c0 + nt*16 + li;
    const float b = bias ? bias[ch] : 0.f;
#pragma unroll
    for (int j = 0; j < 4; ++j) {
      const int gr = m0 + wave*16 + grp*4 + j;
      if (gr < M) {
        float v = acc[nt][j] + b;
        if (RELU) v = fmaxf(v, 0.f);
        C[(size_t)gr*ldc + ch] = v;
      }
    }
  }
}

// ---------------------------------------------------------------------------
// Fused per-static-layer (MFMA): h = relu(agg@Wu^T + bu) -> Hout (ldh) AND
// R = bf16(h) @ bf16(Wm)^T -> Rout (round-15 version, verified).
// ---------------------------------------------------------------------------
__global__ __launch_bounds__(256) void fused_hR_kernel(
    const float* __restrict__ A,
    const float* __restrict__ Wu, const float* __restrict__ bu,
    float* __restrict__ Hout, int ldh,
    const float* __restrict__ Wm,                 // pre-offset +16, ld 80
    float* __restrict__ Rout, int M)
{
  __shared__ short As[64 * 72];
  __shared__ short Ws[64 * 72];
  const int tid = threadIdx.x;
  const int wave = tid >> 6, lane = tid & 63;
  const int grp = lane >> 4, li = lane & 15;
  const int m0 = blockIdx.x * 64;
  const int srow = tid >> 2;
  const int sc16 = (tid & 3) * 16;

  {
    const int gr = m0 + srow;
    stage_tile_bf16(As, A + (size_t)gr*64 + sc16, srow, sc16, gr < M);
    stage_tile_bf16(Ws, Wu + (size_t)srow*64 + sc16, srow, sc16, true);
  }
  __syncthreads();
  f32x4 acc[4];
#pragma unroll
  for (int nt = 0; nt < 4; ++nt) acc[nt] = (f32x4)0.f;
#pragma unroll
  for (int ks = 0; ks < 2; ++ks) {
    const short8v a = *(const short8v*)&As[(wave*16 + li)*72 + ks*32 + grp*8];
#pragma unroll
    for (int nt = 0; nt < 4; ++nt) {
      const short8v b = *(const short8v*)&Ws[(nt*16 + li)*72 + ks*32 + grp*8];
      acc[nt] = __builtin_amdgcn_mfma_f32_16x16x32_bf16(a, b, acc[nt], 0, 0, 0);
    }
  }
  __syncthreads();

  stage_tile_bf16(Ws, Wm + (size_t)srow*80 + sc16, srow, sc16, true);
#pragma unroll
  for (int nt = 0; nt < 4; ++nt) {
    const int ch = nt*16 + li;
    const float b = bu[ch];
#pragma unroll
    for (int j = 0; j < 4; ++j) {
      const int row = wave*16 + grp*4 + j;
      const int gr = m0 + row;
      const float v = fmaxf(acc[nt][j] + b, 0.f);
      if (gr < M) Hout[(size_t)gr*ldh + ch] = v;
      As[row*72 + ch] = f2bf(v);
    }
  }
  __syncthreads();

  f32x4 acc2[4];
#pragma unroll
  for (int nt = 0; nt < 4; ++nt) acc2[nt] = (f32x4)0.f;
#pragma unroll
  for (int ks = 0; ks < 2; ++ks) {
    const short8v a = *(const short8v*)&As[(wave*16 + li)*72 + ks*32 + grp*8];
#pragma unroll
    for (int nt = 0; nt < 4; ++nt) {
      const short8v b = *(const short8v*)&Ws[(nt*16 + li)*72 + ks*32 + grp*8];
      acc2[nt] = __builtin_amdgcn_mfma_f32_16x16x32_bf16(a, b, acc2[nt], 0, 0, 0);
    }
  }
#pragma unroll
  for (int nt = 0; nt < 4; ++nt) {
    const int ch = nt*16 + li;
#pragma unroll
    for (int j = 0; j < 4; ++j) {
      const int gr = m0 + wave*16 + grp*4 + j;
      if (gr < M) Rout[(size_t)gr*64 + ch] = acc2[nt][j];
    }
  }
}

// ---------------------------------------------------------------------------
// Fused output stage (round-16/17 version, verified): h3 in LDS, fu1 in LDS,
// out = [CAT,h3]@f2w[:,64:]^T + fu1@f2w[:,0:64]^T + f2b.
// ---------------------------------------------------------------------------
__global__ __launch_bounds__(256) void fusion_kernel(
    const float* __restrict__ CAT,
    const float* __restrict__ aggv,
    const float* __restrict__ wu3, const float* __restrict__ bu3,
    const float* __restrict__ f1w, const float* __restrict__ f1b,
    const float* __restrict__ f2w, const float* __restrict__ f2bias,
    float* __restrict__ out, int M)
{
  __shared__ short As[64 * 72];
  __shared__ short W1s[64 * 72];
  __shared__ short W2s[64 * 72];
  __shared__ short H3s[64 * 72];
  const int tid = threadIdx.x;
  const int wave = tid >> 6, lane = tid & 63;
  const int grp = lane >> 4, li = lane & 15;
  const int m0 = blockIdx.x * 64;
  const int srow = tid >> 2;
  const int sc16 = (tid & 3) * 16;

  // ---- phase 0: h3 tile ----
  {
    const int gr = m0 + srow;
    stage_tile_bf16(As,  aggv + (size_t)gr*64 + sc16, srow, sc16, gr < M);
    stage_tile_bf16(W1s, wu3 + (size_t)srow*64 + sc16, srow, sc16, true);
  }
  __syncthreads();
  f32x4 acc1[4], acc2[4];
#pragma unroll
  for (int nt = 0; nt < 4; ++nt) { acc1[nt] = (f32x4)0.f; acc2[nt] = (f32x4)0.f; }
#pragma unroll
  for (int ks = 0; ks < 2; ++ks) {
    const short8v a = *(const short8v*)&As[(wave*16 + li)*72 + ks*32 + grp*8];
#pragma unroll
    for (int nt = 0; nt < 4; ++nt) {
      const short8v b = *(const short8v*)&W1s[(nt*16 + li)*72 + ks*32 + grp*8];
      acc1[nt] = __builtin_amdgcn_mfma_f32_16x16x32_bf16(a, b, acc1[nt], 0, 0, 0);
    }
  }
#pragma unroll
  for (int nt = 0; nt < 4; ++nt) {
    const int ch = nt*16 + li;
    const float b = bu3[ch];
#pragma unroll
    for (int j = 0; j < 4; ++j) {
      const int row = wave*16 + grp*4 + j;
      H3s[row*72 + ch] = f2bf(fmaxf(acc1[nt][j] + b, 0.f));
    }
  }
  __syncthreads();

  // ---- main loop: 4 CAT tiles + h3 tile ----
#pragma unroll
  for (int nt = 0; nt < 4; ++nt) acc1[nt] = (f32x4)0.f;
  for (int tile = 0; tile < 5; ++tile) {
    const int kt = tile * 64;
    if (tile < 4) {
      const int gr = m0 + srow;
      stage_tile_bf16(As, CAT + (size_t)gr*320 + kt + sc16, srow, sc16, gr < M);
    }
    stage_tile_bf16(W1s, f1w + (size_t)srow*320 + kt + sc16, srow, sc16, true);
    stage_tile_bf16(W2s, f2w + (size_t)srow*384 + 64 + kt + sc16, srow, sc16, true);
    __syncthreads();
    const short* Ause = (tile < 4) ? As : H3s;
#pragma unroll
    for (int ks = 0; ks < 2; ++ks) {
      const short8v a = *(const short8v*)&Ause[(wave*16 + li)*72 + ks*32 + grp*8];
#pragma unroll
      for (int nt = 0; nt < 4; ++nt) {
        const short8v b1 = *(const short8v*)&W1s[(nt*16 + li)*72 + ks*32 + grp*8];
        const short8v b2 = *(const short8v*)&W2s[(nt*16 + li)*72 + ks*32 + grp*8];
        acc1[nt] = __builtin_amdgcn_mfma_f32_16x16x32_bf16(a, b1, acc1[nt], 0, 0, 0);
        acc2[nt] = __builtin_amdgcn_mfma_f32_16x16x32_bf16(a, b2, acc2[nt], 0, 0, 0);
      }
    }
    __syncthreads();
  }

  // ---- fu1 finish ----
  stage_tile_bf16(W1s, f2w + (size_t)srow*384 + sc16, srow, sc16, true);
#pragma unroll
  for (int nt = 0; nt < 4; ++nt) {
    const int ch = nt*16 + li;
    const float b = f1b[ch];
#pragma unroll
    for (int j = 0; j < 4; ++j) {
      const int row = wave*16 + grp*4 + j;
      As[row*72 + ch] = f2bf(fmaxf(acc1[nt][j] + b, 0.f));
    }
  }
  __syncthreads();
#pragma unroll
  for (int ks = 0; ks < 2; ++ks) {
    const short8v a = *(const short8v*)&As[(wave*16 + li)*72 + ks*32 + grp*8];
#pragma unroll
    for (int nt = 0; nt < 4; ++nt) {
      const short8v b = *(const short8v*)&W1s[(nt*16 + li)*72 + ks*32 + grp*8];
      acc2[nt] = __builtin_amdgcn_mfma_f32_16x16x32_bf16(a, b, acc2[nt], 0, 0, 0);
    }
  }
#pragma unroll
  for (int nt = 0; nt < 4; ++nt) {
    const int ch = nt*16 + li;
    const float b = f2bias[ch];
#pragma unroll
    for (int j = 0; j < 4; ++j) {
      const int gr = m0 + wave*16 + grp*4 + j;
      if (gr < M) out[(size_t)gr*64 + ch] = acc2[nt][j] + b;
    }
  }
}

// ---------------------------------------------------------------------------
// Dynamic conv via MFMA (bf16), unchanged.
// ---------------------------------------------------------------------------
#define TPW 4   // targets per wave

__global__ __launch_bounds__(256) void dyn_mfma_kernel(
    const float* __restrict__ PQ,
    const float* __restrict__ W2, const float* __restrict__ b2,
    const int* __restrict__ knn, float* __restrict__ out, int ldo, int n)
{
  __shared__ short w2s[64 * 136];
  __shared__ short Ts[4][17 * 136];
  const int tid = threadIdx.x;
  const int wave = tid >> 6, lane = tid & 63;

  for (int idx = tid; idx < 64 * 128; idx += 256) {
    const int c = idx >> 7, k = idx & 127;
    w2s[c*136 + k] = f2bf(W2[c*128 + k]);
  }
  __syncthreads();

  short8v bfr[4][4];
#pragma unroll
  for (int nt = 0; nt < 4; ++nt)
#pragma unroll
    for (int kt = 0; kt < 4; ++kt)
      bfr[nt][kt] = *(const short8v*)&w2s[(nt*16 + (lane&15))*136 +
                                          kt*32 + (lane>>4)*8];
  const float b2v = b2[lane];
  short* T = Ts[wave];

  for (int tg = 0; tg < TPW; ++tg) {
    const int i = (blockIdx.x * 4 + wave) * TPW + tg;
    if (i >= n) break;
    const size_t i16 = (size_t)i * 16;

    for (int s = 0; s < 9; ++s) {
      const int slot = lane + 64*s;
      if (slot < 544) {
        const int row = slot >> 5, k4 = slot & 31;
        const int j = (row < 16) ? knn[i16 + row] : i;
        const float4 p = *(const float4*)(PQ + (size_t)i*256 + k4*4);
        const float4 q = *(const float4*)(PQ + (size_t)j*256 + 128 + k4*4);
        const float t0 = fmaxf(p.x + q.x, 0.f), t1 = fmaxf(p.y + q.y, 0.f);
        const float t2 = fmaxf(p.z + q.z, 0.f), t3 = fmaxf(p.w + q.w, 0.f);
        int2 w;
        w.x = ((int)(unsigned short)f2bf(t1) << 16) | (unsigned short)f2bf(t0);
        w.y = ((int)(unsigned short)f2bf(t3) << 16) | (unsigned short)f2bf(t2);
        *(int2*)&T[row*136 + k4*4] = w;
      }
    }

    f32x4 acc0[4], acc1[4];
#pragma unroll
    for (int nt = 0; nt < 4; ++nt) {
      acc0[nt] = (f32x4)0.f;
      acc1[nt] = (f32x4)0.f;
    }
#pragma unroll
    for (int kt = 0; kt < 4; ++kt) {
      const short8v a1 = *(const short8v*)&T[(lane&15)*136 + kt*32 + (lane>>4)*8];
      const short8v a2 = *(const short8v*)&T[16*136 + kt*32 + (lane>>4)*8];
#pragma unroll
      for (int nt = 0; nt < 4; ++nt) {
        acc0[nt] = __builtin_amdgcn_mfma_f32_16x16x32_bf16(a1, bfr[nt][kt], acc0[nt], 0, 0, 0);
        acc1[nt] = __builtin_amdgcn_mfma_f32_16x16x32_bf16(a2, bfr[nt][kt], acc1[nt], 0, 0, 0);
      }
    }

    float v[4];
#pragma unroll
    for (int nt = 0; nt < 4; ++nt) {
      float m = fmaxf(fmaxf(acc0[nt][0], acc0[nt][1]),
                      fmaxf(acc0[nt][2], acc0[nt][3]));
      m = fmaxf(m, acc1[nt][0]);
      m = fmaxf(m, __shfl_xor(m, 16, 64));
      m = fmaxf(m, __shfl_xor(m, 32, 64));
      v[nt] = m;
    }
    const int g = lane >> 4;
    float r = v[0];
    r = (g == 1) ? v[1] : r;
    r = (g == 2) ? v[2] : r;
    r = (g == 3) ? v[3] : r;
    out[(size_t)i*ldo + lane] = fmaxf(r + b2v, 0.f);
  }
}

// ---------------------------------------------------------------------------
// Host orchestration
// ---------------------------------------------------------------------------
extern "C" void kernel_launch(void* const* d_in, const int* in_sizes, int n_in,
                              void* d_out, int out_size, void* d_ws, size_t ws_size,
                              hipStream_t stream)
{
  const float* x   = (const float*)d_in[0];
  const int*   ei  = (const int*)d_in[1];
  const float* ea  = (const float*)d_in[2];
  const float* loc = (const float*)d_in[3];
  const float* sg_wm[3] = {(const float*)d_in[5],  (const float*)d_in[9],  (const float*)d_in[13]};
  const float* sg_bm[3] = {(const float*)d_in[6],  (const float*)d_in[10], (const float*)d_in[14]};
  const float* sg_wu[3] = {(const float*)d_in[7],  (const float*)d_in[11], (const float*)d_in[15]};
  const float* sg_bu[3] = {(const float*)d_in[8],  (const float*)d_in[12], (const float*)d_in[16]};
  const float* dg_w1[2] = {(const float*)d_in[17], (const float*)d_in[21]};
  const float* dg_b1[2] = {(const float*)d_in[18], (const float*)d_in[22]};
  const float* dg_w2[2] = {(const float*)d_in[19], (const float*)d_in[23]};
  const float* dg_b2[2] = {(const float*)d_in[20], (const float*)d_in[24]};
  const float* f1_w = (const float*)d_in[25];
  const float* f1_b = (const float*)d_in[26];
  const float* f2_w = (const float*)d_in[27];
  const float* f2_b = (const float*)d_in[28];
  float* out = (float*)d_out;

  const int n    = in_sizes[0] / 64;
  const int Etot = in_sizes[1] / 2;
  const int* srcp = ei;
  const int* dstp = ei + Etot;

  char* basep = (char*)d_ws;
  size_t cur = 0;
  auto alloc = [&](size_t bytes) -> void* {
    void* p = basep + cur;
    cur = (cur + bytes + 255) & ~(size_t)255;
    return p;
  };
  float* CAT  = (float*)alloc((size_t)n * 320 * 4);   // cols 256.. unused
  float* Rb   = (float*)alloc((size_t)n * 64 * 4);
  float* PQb  = (float*)alloc((size_t)n * 256 * 4);
  float* agg  = (float*)alloc((size_t)n * 64 * 4);
  float* wpq[2];
  float* bpq[2];
  wpq[0] = (float*)alloc(256 * 64 * 4);  bpq[0] = (float*)alloc(256 * 4);
  wpq[1] = (float*)alloc(256 * 64 * 4);  bpq[1] = (float*)alloc(256 * 4);
  int* knnb   = (int*)alloc((size_t)n * 16 * 4);
  int* zeros     = (int*)alloc((size_t)(2*KNN_NC + 2*n) * 4);
  int* cellcount = zeros;
  int* cellfill  = zeros + KNN_NC;
  int* deg       = zeros + 2*KNN_NC;
  int* dfill     = zeros + 2*KNN_NC + n;
  int* cellstart = (int*)alloc((size_t)(KNN_NC + 1) * 4);
  int* cellidb   = (int*)alloc((size_t)n * 4);
  float* locs4s  = (float*)alloc((size_t)n * 4 * 4);
  int* oidx      = (int*)alloc((size_t)n * 4);
  int* rowptr    = (int*)alloc((size_t)(n + 1) * 4);
  int* cs_src    = (int*)alloc((size_t)Etot * 4);
  int* cs_eid    = (int*)alloc((size_t)Etot * 4);
  short* ea_csr  = (short*)alloc((size_t)Etot * 16 * 2);   // bf16
  (void)ws_size; (void)n_in; (void)out_size;

  const int nbE = (Etot + 255) / 256;
  const int mb = (n + 63) / 64;

  hipMemsetAsync(zeros, 0, (size_t)(2*KNN_NC + 2*n) * 4, stream);
  count2_kernel<<<nbE, 256, 0, stream>>>(loc, cellcount, cellidb, n,
                                         dstp, deg, Etot);
  scan2_kernel<<<2, 1024, 0, stream>>>(cellcount, cellstart, KNN_NC,
                                       (KNN_NC + 1023) / 1024,
                                       deg, rowptr, n, (n + 1023) / 1024);
  scatter2_kernel<<<nbE, 256, 0, stream>>>(loc, cellidb, cellstart, cellfill,
                                           locs4s, oidx, n,
                                           srcp, dstp, rowptr, dfill,
                                           cs_src, cs_eid, Etot);
  const int KB = (n + 3) / 4;
  const int EB = (Etot + 255) / 256;      // one edge per thread
  mega_kernel<<<KB + EB + 64 + mb, 256, 0, stream>>>(
      locs4s, oidx, cellstart, knnb, n,
      ea, cs_eid, ea_csr, Etot,
      dg_w1[0], dg_b1[0], wpq[0], bpq[0],
      dg_w1[1], dg_b1[1], wpq[1], bpq[1],
      x, sg_wm[0] + 16, Rb,
      KB, EB);

  auto lin = [&](const float* A, int lda, const float* W, int ldw, const float* bias,
                 float* C, int ldc, int K, int ncols, bool relu) {
    dim3 grid(mb, ncols / 64);
    if (relu) linear_kernel<true ><<<grid, 256, 0, stream>>>(A, lda, W, ldw, bias, C, ldc, n, K);
    else      linear_kernel<false><<<grid, 256, 0, stream>>>(A, lda, W, ldw, bias, C, ldc, n, K);
  };

  const int smb = (n + 4*TPW_S - 1) / (4*TPW_S);
  // static layers: (R1 from mega) -> msg1 -> h1,R2 -> msg2 -> h2,R3 -> msg3
  static_msg_kernel<<<smb, 256, 0, stream>>>(Rb, ea_csr, sg_wm[0], sg_bm[0],
                                             cs_src, rowptr, agg, n);
  fused_hR_kernel<<<mb, 256, 0, stream>>>(agg, sg_wu[0], sg_bu[0],
                                          CAT + 0, 320,
                                          sg_wm[1] + 16, Rb, n);      // h1, R2
  static_msg_kernel<<<smb, 256, 0, stream>>>(Rb, ea_csr, sg_wm[1], sg_bm[1],
                                             cs_src, rowptr, agg, n);
  fused_hR_kernel<<<mb, 256, 0, stream>>>(agg, sg_wu[1], sg_bu[1],
                                          CAT + 192, 320,
                                          sg_wm[2] + 16, Rb, n);      // h2, R3
  static_msg_kernel<<<smb, 256, 0, stream>>>(Rb, ea_csr, sg_wm[2], sg_bm[2],
                                             cs_src, rowptr, agg, n);
  // (h3 computed inside fusion_kernel from agg)

  // dynamic layers: h1 -> g1(CAT+64); g1 -> g2(CAT+128)
  const float* din[2] = {CAT + 0, CAT + 64};
  float* doutp[2] = {CAT + 64, CAT + 128};
  const int db = (n + 4*TPW - 1) / (4*TPW);
  for (int l = 0; l < 2; ++l) {
    lin(din[l], 320, wpq[l], 64, bpq[l], PQb, 256, 64, 256, false);
    dyn_mfma_kernel<<<db, 256, 0, stream>>>(PQb, dg_w2[l], dg_b2[l],
                                            knnb, doutp[l], 320, n);
  }

  // fused output stage (includes h3)
  fusion_kernel<<<mb, 256, 0, stream>>>(CAT, agg, sg_wu[2], sg_bu[2],
                                        f1_w, f1_b, f2_w, f2_b, out, n);
}

// Round 20
// 280.158 us; speedup vs baseline: 1.7836x; 1.0547x over previous
//
#include <hip/hip_runtime.h>

#define INF_F __builtin_inff()

typedef __attribute__((ext_vector_type(8))) short short8v;  // 8 bf16
typedef __attribute__((ext_vector_type(4))) float f32x4;
typedef unsigned long long ull;

__device__ __forceinline__ short f2bf(float x) {
  const unsigned u = __float_as_uint(x);
  return (short)((u + 0x7FFFu + ((u >> 16) & 1u)) >> 16);   // RNE
}

__device__ __forceinline__ unsigned mbcnt64(ull m) {
  return __builtin_amdgcn_mbcnt_hi((unsigned)(m >> 32),
                                   __builtin_amdgcn_mbcnt_lo((unsigned)m, 0u));
}

// ===========================================================================
// Spatial-bin exact kNN, WAVE-per-target, G=5, materialized flat positions,
// per-target face bound for escalation (round-13..17 config, measured ~73 us).
// ===========================================================================
#define KNN_G 5
#define KNN_NC (KNN_G*KNN_G*KNN_G*KNN_G)   // 625
#define KNN_PCAP 1600

// ---- merged init kernels ---------------------------------------------------
__global__ __launch_bounds__(256) void count2_kernel(
    const float* __restrict__ loc, int* __restrict__ cellcount,
    int* __restrict__ cellid, int n,
    const int* __restrict__ dst, int* __restrict__ deg, int E)
{
  const int i = blockIdx.x * 256 + threadIdx.x;
  if (i < n) {
    const float4 l = *(const float4*)(loc + (size_t)i*4);
    const int cx = min(KNN_G-1, (int)(l.x * (float)KNN_G));
    const int cy = min(KNN_G-1, (int)(l.y * (float)KNN_G));
    const int cz = min(KNN_G-1, (int)(l.z * (float)KNN_G));
    const int cw = min(KNN_G-1, (int)(l.w * (float)KNN_G));
    const int c = ((cx*KNN_G + cy)*KNN_G + cz)*KNN_G + cw;
    cellid[i] = c;
    atomicAdd(&cellcount[c], 1);
  }
  if (i < E) atomicAdd(&deg[dst[i]], 1);
}

__device__ __forceinline__ void scan1b_body(
    const int* __restrict__ in, int* __restrict__ out, int n, int per)
{
  __shared__ int part[1024];
  const int t = threadIdx.x;
  const int lo = t * per, hi = min(lo + per, n);
  int sum = 0;
  for (int idx = lo; idx < hi; ++idx) sum += in[idx];
  int v = sum;
  part[t] = v;
  __syncthreads();
  for (int off = 1; off < 1024; off <<= 1) {
    const int o = (t >= off) ? part[t - off] : 0;
    __syncthreads();
    v += o;
    part[t] = v;
    __syncthreads();
  }
  int run = v - sum;
  for (int idx = lo; idx < hi; ++idx) { out[idx] = run; run += in[idx]; }
  if (t == 1023) out[n] = v;
}

__global__ __launch_bounds__(1024) void scan2_kernel(
    const int* __restrict__ inA, int* __restrict__ outA, int nA, int perA,
    const int* __restrict__ inB, int* __restrict__ outB, int nB, int perB)
{
  if (blockIdx.x == 0) scan1b_body(inA, outA, nA, perA);
  else                 scan1b_body(inB, outB, nB, perB);
}

__global__ __launch_bounds__(256) void scatter2_kernel(
    const float* __restrict__ loc, const int* __restrict__ cellid,
    const int* __restrict__ cellstart, int* __restrict__ cellfill,
    float* __restrict__ locs4s, int* __restrict__ oidx, int n,
    const int* __restrict__ srcs, const int* __restrict__ dsts,
    const int* __restrict__ rowptr, int* __restrict__ dfill,
    int* __restrict__ cs_src, int* __restrict__ cs_eid, int E)
{
  const int i = blockIdx.x * 256 + threadIdx.x;
  if (i < n) {
    const int c = cellid[i];
    const int pos = cellstart[c] + atomicAdd(&cellfill[c], 1);
    *(float4*)(locs4s + (size_t)pos*4) = *(const float4*)(loc + (size_t)i*4);
    oidx[pos] = i;
  }
  if (i < E) {
    const int d = dsts[i];
    const int pos = rowptr[d] + atomicAdd(&dfill[d], 1);
    cs_src[pos] = srcs[i];
    cs_eid[pos] = i;
  }
}

// ---- kNN selection helpers -------------------------------------------------
__device__ __forceinline__ ull
knn_refine16(ull* __restrict__ B, int cnt, int lane, ull& topsave)
{
  ull v[5];
#pragma unroll
  for (int s = 0; s < 5; ++s) {
    const int idx = lane + 64*s;
    v[s] = (idx < cnt) ? B[idx] : ~0ull;
  }
  ull tau = ~0ull;
#pragma unroll
  for (int r = 0; r < 16; ++r) {
    ull m = v[0]; int sl = 0;
#pragma unroll
    for (int s = 1; s < 5; ++s) if (v[s] < m) { m = v[s]; sl = s; }
    ull mm = m;
#pragma unroll
    for (int off = 32; off >= 1; off >>= 1) {
      const ull o = __shfl_xor(mm, off, 64);
      if (o < mm) mm = o;
    }
    const bool killer = (m == mm);
#pragma unroll
    for (int s = 0; s < 5; ++s) if (killer && sl == s) v[s] = ~0ull;
    if (lane == r) topsave = mm;
    tau = mm;            // after round 15: exact 16th-smallest
  }
  if (lane < 16) B[lane] = topsave;
  return tau;
}

__device__ __forceinline__ int
knn_filter(ull* __restrict__ B, int cnt, int lane, ull& tau)
{
  ull v[5];
#pragma unroll
  for (int s = 0; s < 5; ++s) {
    const int idx = lane + 64*s;
    v[s] = (idx < cnt) ? B[idx] : ~0ull;
  }
  ull g = v[0];
#pragma unroll
  for (int s = 1; s < 5; ++s) if (v[s] < g) g = v[s];
  { ull o = __shfl_xor(g, 1, 64); if (o < g) g = o;
    o = __shfl_xor(g, 2, 64); if (o < g) g = o; }
  ull t = g;
#pragma unroll
  for (int off = 4; off <= 32; off <<= 1) {
    const ull o = __shfl_xor(t, off, 64);
    if (o > t) t = o;
  }
  int nc = 0;
#pragma unroll
  for (int s = 0; s < 5; ++s) {
    const bool keep = (v[s] <= t) && (v[s] != ~0ull);
    const ull mask = __ballot(keep);
    if (mask) {
      const unsigned pre = mbcnt64(mask);
      if (keep) B[nc + pre] = v[s];
      nc += (int)__popcll(mask);
    }
  }
  tau = t;
  return nc;
}

__device__ void knn_body(int blk, ull* __restrict__ Bs, int* __restrict__ PosAll,
                         const float* __restrict__ locs4s,
                         const int* __restrict__ oidx,
                         const int* __restrict__ cellstart,
                         int* __restrict__ knn, int n)
{
#pragma clang fp contract(off)
  constexpr int TRIG = 256;
  const int wave = threadIdx.x >> 6, lane = threadIdx.x & 63;
  const int t = blk * 4 + wave;          // sorted position of target
  if (t >= n) return;                    // wave-uniform exit
  ull* B = Bs + wave * 320;
  int* Pos = PosAll + wave * KNN_PCAP;

  const float4 L = *(const float4*)(locs4s + (size_t)t*4);
  const float tx = L.x, ty = L.y, tz = L.z, tw = L.w;
  const int cx = min(KNN_G-1, (int)(tx * (float)KNN_G));
  const int cy = min(KNN_G-1, (int)(ty * (float)KNN_G));
  const int cz = min(KNN_G-1, (int)(tz * (float)KNN_G));
  const int cw = min(KNN_G-1, (int)(tw * (float)KNN_G));

  ull tau = ~0ull;
  ull topsave = ~0ull;
  int cnt = 0;

  auto boundB = [&](int mr) -> float {
    const float w = 1.0f / (float)KNN_G;
    float Bv = INF_F;
    if (cx - mr >= 1)         Bv = fminf(Bv, tx - (float)(cx - mr) * w);
    if (cx + mr <= KNN_G - 2) Bv = fminf(Bv, (float)(cx + mr + 1) * w - tx);
    if (cy - mr >= 1)         Bv = fminf(Bv, ty - (float)(cy - mr) * w);
    if (cy + mr <= KNN_G - 2) Bv = fminf(Bv, (float)(cy + mr + 1) * w - ty);
    if (cz - mr >= 1)         Bv = fminf(Bv, tz - (float)(cz - mr) * w);
    if (cz + mr <= KNN_G - 2) Bv = fminf(Bv, (float)(cz + mr + 1) * w - tz);
    if (cw - mr >= 1)         Bv = fminf(Bv, tw - (float)(cw - mr) * w);
    if (cw + mr <= KNN_G - 2) Bv = fminf(Bv, (float)(cw + mr + 1) * w - tw);
    return Bv;
  };

  auto do_range = [&](int ps, int pe) {
    for (int p0 = ps; p0 < pe; p0 += 64) {
      const int p = p0 + lane;
      ull key = ~0ull;
      if (p < pe && p != t) {
        const float4 q = *(const float4*)(locs4s + (size_t)p*4);
        const int oj = oidx[p];
        const float a0 = q.x - tx, a1 = q.y - ty, a2 = q.z - tz, a3 = q.w - tw;
        const float s0 = a0*a0, s1 = a1*a1, s2 = a2*a2, s3 = a3*a3;
        const float d = ((s0 + s1) + s2) + s3;
        key = ((ull)__float_as_uint(d) << 32) | (unsigned)oj;
      }
      const bool surv = key < tau;
      const ull mask = __ballot(surv);
      if (mask) {
        const unsigned pre = mbcnt64(mask);
        if (surv) B[cnt + pre] = key;
        cnt += (int)__popcll(mask);
        if (cnt > TRIG) cnt = knn_filter(B, cnt, lane, tau);
      }
    }
  };

  // ---- level 0: radius-1 block as a materialized flat position list ----
  int psv = 0, pev = 0;
  if (lane < 27) {
    const int cr = (lane == 0) ? 13 : (lane <= 13 ? lane - 1 : lane);
    const int ax = cx + (cr / 9) - 1;
    const int ay = cy + ((cr / 3) % 3) - 1;
    const int az = cz + (cr % 3) - 1;
    if (ax >= 0 && ax < KNN_G && ay >= 0 && ay < KNN_G &&
        az >= 0 && az < KNN_G) {
      const int base = ((ax*KNN_G + ay)*KNN_G + az)*KNN_G;
      const int wlo = max(cw-1, 0), whi = min(cw+1, KNN_G-1);
      psv = cellstart[base + wlo];
      pev = cellstart[base + whi + 1];
    }
  }
  const int len = max(pev - psv, 0);
  int cum = len;
#pragma unroll
  for (int off = 1; off < 64; off <<= 1) {
    const int o = __shfl_up(cum, off, 64);
    if (lane >= off) cum += o;
  }
  const int T = __shfl(cum, 63, 64);
  const int startv = cum - len;

  for (int p = psv, f = startv; p < pev && f < KNN_PCAP; ++p, ++f) Pos[f] = p;

  const int Tb = min(T, KNN_PCAP);
  const int Tm1b = Tb - 1;
  float4 qn; int ojn = 0, pgn = 0; bool vn = false;
  {
    vn = lane < Tb;
    pgn = Pos[min(lane, Tm1b)];
    qn = *(const float4*)(locs4s + (size_t)pgn*4);
    ojn = oidx[pgn];
  }
  for (int f0 = 0; f0 < Tb; f0 += 64) {
    const float4 qc = qn; const int ojc = ojn, pgc = pgn; const bool vc = vn;
    const int fN = f0 + 64 + lane;
    vn = fN < Tb;
    if (f0 + 64 < Tb) {
      pgn = Pos[min(fN, Tm1b)];
      qn = *(const float4*)(locs4s + (size_t)pgn*4);
      ojn = oidx[pgn];
    }
    ull key = ~0ull;
    if (vc && pgc != t) {
      const float a0 = qc.x - tx, a1 = qc.y - ty, a2 = qc.z - tz, a3 = qc.w - tw;
      const float s0 = a0*a0, s1 = a1*a1, s2 = a2*a2, s3 = a3*a3;
      const float d = ((s0 + s1) + s2) + s3;
      key = ((ull)__float_as_uint(d) << 32) | (unsigned)ojc;
    }
    const bool surv = key < tau;
    const ull mask = __ballot(surv);
    if (mask) {
      const unsigned pre = mbcnt64(mask);
      if (surv) B[cnt + pre] = key;
      cnt += (int)__popcll(mask);
      if (cnt > TRIG) cnt = knn_filter(B, cnt, lane, tau);
    }
  }
  if (T > KNN_PCAP) {
    for (int r = 0; r < 27; ++r) {
      const int st = __shfl(startv, r, 64);
      const int ps = __shfl(psv, r, 64);
      const int pe = __shfl(pev, r, 64);
      const int done = min(max(KNN_PCAP - st, 0), pe - ps);
      if (ps + done < pe) do_range(ps + done, pe);
    }
  }

  // ---- shells m = 2..G-1 (rare; exact refine + per-target bound check) ----
  for (int m = 2; m <= KNN_G - 1; ++m) {
    if (cnt > 16) { tau = knn_refine16(B, cnt, lane, topsave); cnt = 16; }
    if (tau != ~0ull) {
      const float taud = __uint_as_float((unsigned)(tau >> 32));
      const float Bv = boundB(m - 1);
      if (Bv == INF_F || taud < Bv * Bv * 0.99999f) break;
    }
    const int xlo = max(cx-m, 0), xhi = min(cx+m, KNN_G-1);
    for (int ax = xlo; ax <= xhi; ++ax) {
      const bool xe = (ax == cx-m) || (ax == cx+m);
      const int ylo = max(cy-m, 0), yhi = min(cy+m, KNN_G-1);
      for (int ay = ylo; ay <= yhi; ++ay) {
        const bool ye = (ay == cy-m) || (ay == cy+m);
        const int zlo = max(cz-m, 0), zhi = min(cz+m, KNN_G-1);
        for (int az = zlo; az <= zhi; ++az) {
          const bool ze = (az == cz-m) || (az == cz+m);
          const int base = ((ax*KNN_G + ay)*KNN_G + az)*KNN_G;
          if (xe | ye | ze) {
            const int wlo = max(cw-m, 0), whi = min(cw+m, KNN_G-1);
            do_range(cellstart[base+wlo], cellstart[base+whi+1]);
          } else {
            if (cw-m >= 0) {
              const int c = base + cw - m;
              do_range(cellstart[c], cellstart[c+1]);
            }
            if (cw+m <= KNN_G-1) {
              const int c = base + cw + m;
              do_range(cellstart[c], cellstart[c+1]);
            }
          }
        }
      }
    }
  }
  (void)knn_refine16(B, cnt, lane, topsave);   // exact top-16
  const int i = oidx[t];
  if (lane < 16) knn[(size_t)i*16 + lane] = (int)(topsave & 0xFFFFFFFFull);
}

// ---------------------------------------------------------------------------
// Staging helper: convert a 64x64 fp32 tile row-chunk to bf16 LDS (pitch 72).
// ---------------------------------------------------------------------------
__device__ __forceinline__ void stage_tile_bf16(
    short* __restrict__ S, const float* __restrict__ src, int srow, int sc16,
    bool valid)
{
  short tmp[16];
  if (valid) {
#pragma unroll
    for (int u = 0; u < 4; ++u) {
      const float4 v = *(const float4*)(src + u*4);
      tmp[u*4+0] = f2bf(v.x); tmp[u*4+1] = f2bf(v.y);
      tmp[u*4+2] = f2bf(v.z); tmp[u*4+3] = f2bf(v.w);
    }
  } else {
#pragma unroll
    for (int u = 0; u < 16; ++u) tmp[u] = 0;
  }
  *(short8v*)&S[srow*72 + sc16]     = *(short8v*)&tmp[0];
  *(short8v*)&S[srow*72 + sc16 + 8] = *(short8v*)&tmp[8];
}

// ---------------------------------------------------------------------------
// Msg body (static conv message + segment max, 2 dsts per wave) — shared by
// the standalone msg kernel and the combo kernels. Identical arithmetic to
// the verified round-17 static_msg_kernel.
// ---------------------------------------------------------------------------
#define TPW_S 2

__device__ __forceinline__ void msg_body(
    int blk,
    const float* __restrict__ R, const short* __restrict__ eac,
    const float* __restrict__ wm, const float* __restrict__ bm,
    const int* __restrict__ cs_src, const int* __restrict__ rowptr,
    float* __restrict__ agg, int n)
{
  const int wave = threadIdx.x >> 6, lane = threadIdx.x & 63;
  const int grp = lane >> 4, li = lane & 15;

  short8v bfr[4];
  float bmv[4];
#pragma unroll
  for (int nt = 0; nt < 4; ++nt) {
    short8v b = (short8v)0;
    if (grp < 2) {
      const int ch = nt*16 + li;
#pragma unroll
      for (int j = 0; j < 8; ++j) b[j] = f2bf(wm[ch*80 + grp*8 + j]);
    }
    bfr[nt] = b;
    bmv[nt] = bm[nt*16 + li];
  }
  const f32x4 zero = (f32x4)0.f;

  for (int tg = 0; tg < TPW_S; ++tg) {
    const int d = (blk * 4 + wave) * TPW_S + tg;
    if (d >= n) break;                        // wave-uniform
    const int beg = rowptr[d], end = rowptr[d+1];
    const int deg = end - beg;
    float basev[4];
#pragma unroll
    for (int nt = 0; nt < 4; ++nt)
      basev[nt] = bmv[nt] - R[(size_t)d*64 + nt*16 + li];

    float vmax[4] = {0.f, 0.f, 0.f, 0.f};
    for (int m0 = 0; m0 < deg; m0 += 16) {
      short8v a = (short8v)0;
      const int erow = m0 + li;
      if (grp < 2 && erow < deg)
        a = *(const short8v*)(eac + (size_t)(beg + erow)*16 + grp*8);
      f32x4 Dv[4];
#pragma unroll
      for (int nt = 0; nt < 4; ++nt)
        Dv[nt] = __builtin_amdgcn_mfma_f32_16x16x32_bf16(a, bfr[nt], zero, 0, 0, 0);
#pragma unroll
      for (int j = 0; j < 4; ++j) {
        const int m = m0 + grp*4 + j;
        if (m < deg) {
          const int s = cs_src[beg + m];
          const float* Rs = R + (size_t)s*64;
#pragma unroll
          for (int nt = 0; nt < 4; ++nt) {
            const float acc = Dv[nt][j] + Rs[nt*16 + li] + basev[nt];
            vmax[nt] = fmaxf(vmax[nt], fmaxf(acc, 0.f));
          }
        }
      }
    }
#pragma unroll
    for (int nt = 0; nt < 4; ++nt) {
      float m = vmax[nt];
      m = fmaxf(m, __shfl_xor(m, 16, 64));
      m = fmaxf(m, __shfl_xor(m, 32, 64));
      vmax[nt] = m;
    }
    float r = vmax[0];
    r = (grp == 1) ? vmax[1] : r;
    r = (grp == 2) ? vmax[2] : r;
    r = (grp == 3) ? vmax[3] : r;
    agg[(size_t)d*64 + lane] = r;
  }
}

// ---------------------------------------------------------------------------
// Linear body (bf16 MFMA, round-14 verified) on caller-carved LDS.
// ---------------------------------------------------------------------------
template<bool RELU>
__device__ __forceinline__ void lin_body(
    short* __restrict__ As, short* __restrict__ Ws,
    int bx, int by,
    const float* __restrict__ A, int lda,
    const float* __restrict__ W, int ldw,
    const float* __restrict__ bias,
    float* __restrict__ C, int ldc, int M, int K)
{
  const int tid = threadIdx.x;
  const int wave = tid >> 6, lane = tid & 63;
  const int grp = lane >> 4, li = lane & 15;
  const int m0 = bx * 64;
  const int c0 = by * 64;

  f32x4 acc[4];
#pragma unroll
  for (int nt = 0; nt < 4; ++nt) acc[nt] = (f32x4)0.f;

  const int srow = tid >> 2;
  const int sc16 = (tid & 3) * 16;

  for (int kt = 0; kt < K; kt += 64) {
    const int gr = m0 + srow;
    stage_tile_bf16(As, A + (size_t)gr*lda + kt + sc16, srow, sc16, gr < M);
    stage_tile_bf16(Ws, W + (size_t)(c0 + srow)*ldw + kt + sc16, srow, sc16, true);
    __syncthreads();
#pragma unroll
    for (int ks = 0; ks < 2; ++ks) {
      const short8v a = *(const short8v*)&As[(wave*16 + li)*72 + ks*32 + grp*8];
#pragma unroll
      for (int nt = 0; nt < 4; ++nt) {
        const short8v b = *(const short8v*)&Ws[(nt*16 + li)*72 + ks*32 + grp*8];
        acc[nt] = __builtin_amdgcn_mfma_f32_16x16x32_bf16(a, b, acc[nt], 0, 0, 0);
      }
    }
    __syncthreads();
  }

#pragma unroll
  for (int nt = 0; nt < 4; ++nt) {
    const int ch = c0 + nt*16 + li;
    const float b = bias ? bias[ch] : 0.f;
#pragma unroll
    for (int j = 0; j < 4; ++j) {
      const int gr = m0 + wave*16 + grp*4 + j;
      if (gr < M) {
        float v = acc[nt][j] + b;
        if (RELU) v = fmaxf(v, 0.f);
        C[(size_t)gr*ldc + ch] = v;
      }
    }
  }
}

// ---------------------------------------------------------------------------
// fused_hR body (round-15 verified) on caller-carved LDS.
// ---------------------------------------------------------------------------
__device__ __forceinline__ void hR_body(
    short* __restrict__ As, short* __restrict__ Ws, int bx,
    const float* __restrict__ A,
    const float* __restrict__ Wu, const float* __restrict__ bu,
    float* __restrict__ Hout, int ldh,
    const float* __restrict__ Wm,                 // pre-offset +16, ld 80
    float* __restrict__ Rout, int M)
{
  const int tid = threadIdx.x;
  const int wave = tid >> 6, lane = tid & 63;
  const int grp = lane >> 4, li = lane & 15;
  const int m0 = bx * 64;
  const int srow = tid >> 2;
  const int sc16 = (tid & 3) * 16;

  {
    const int gr = m0 + srow;
    stage_tile_bf16(As, A + (size_t)gr*64 + sc16, srow, sc16, gr < M);
    stage_tile_bf16(Ws, Wu + (size_t)srow*64 + sc16, srow, sc16, true);
  }
  __syncthreads();
  f32x4 acc[4];
#pragma unroll
  for (int nt = 0; nt < 4; ++nt) acc[nt] = (f32x4)0.f;
#pragma unroll
  for (int ks = 0; ks < 2; ++ks) {
    const short8v a = *(const short8v*)&As[(wave*16 + li)*72 + ks*32 + grp*8];
#pragma unroll
    for (int nt = 0; nt < 4; ++nt) {
      const short8v b = *(const short8v*)&Ws[(nt*16 + li)*72 + ks*32 + grp*8];
      acc[nt] = __builtin_amdgcn_mfma_f32_16x16x32_bf16(a, b, acc[nt], 0, 0, 0);
    }
  }
  __syncthreads();

  stage_tile_bf16(Ws, Wm + (size_t)srow*80 + sc16, srow, sc16, true);
#pragma unroll
  for (int nt = 0; nt < 4; ++nt) {
    const int ch = nt*16 + li;
    const float b = bu[ch];
#pragma unroll
    for (int j = 0; j < 4; ++j) {
      const int row = wave*16 + grp*4 + j;
      const int gr = m0 + row;
      const float v = fmaxf(acc[nt][j] + b, 0.f);
      if (gr < M) Hout[(size_t)gr*ldh + ch] = v;
      As[row*72 + ch] = f2bf(v);
    }
  }
  __syncthreads();

  f32x4 acc2[4];
#pragma unroll
  for (int nt = 0; nt < 4; ++nt) acc2[nt] = (f32x4)0.f;
#pragma unroll
  for (int ks = 0; ks < 2; ++ks) {
    const short8v a = *(const short8v*)&As[(wave*16 + li)*72 + ks*32 + grp*8];
#pragma unroll
    for (int nt = 0; nt < 4; ++nt) {
      const short8v b = *(const short8v*)&Ws[(nt*16 + li)*72 + ks*32 + grp*8];
      acc2[nt] = __builtin_amdgcn_mfma_f32_16x16x32_bf16(a, b, acc2[nt], 0, 0, 0);
    }
  }
#pragma unroll
  for (int nt = 0; nt < 4; ++nt) {
    const int ch = nt*16 + li;
#pragma unroll
    for (int j = 0; j < 4; ++j) {
      const int gr = m0 + wave*16 + grp*4 + j;
      if (gr < M) Rout[(size_t)gr*64 + ch] = acc2[nt][j];
    }
  }
}

// ---------------------------------------------------------------------------
// dyn conv body (round-6 verified) on caller-carved LDS.
// ---------------------------------------------------------------------------
#define TPW 4   // targets per wave

__device__ __forceinline__ void dyn_body(
    short* __restrict__ w2s, short* __restrict__ TsAll, int blk,
    const float* __restrict__ PQ,
    const float* __restrict__ W2, const float* __restrict__ b2,
    const int* __restrict__ knn, float* __restrict__ out, int ldo, int n)
{
  const int tid = threadIdx.x;
  const int wave = tid >> 6, lane = tid & 63;

  for (int idx = tid; idx < 64 * 128; idx += 256) {
    const int c = idx >> 7, k = idx & 127;
    w2s[c*136 + k] = f2bf(W2[c*128 + k]);
  }
  __syncthreads();

  short8v bfr[4][4];
#pragma unroll
  for (int nt = 0; nt < 4; ++nt)
#pragma unroll
    for (int kt = 0; kt < 4; ++kt)
      bfr[nt][kt] = *(const short8v*)&w2s[(nt*16 + (lane&15))*136 +
                                          kt*32 + (lane>>4)*8];
  const float b2v = b2[lane];
  short* T = TsAll + wave * (17*136);

  for (int tg = 0; tg < TPW; ++tg) {
    const int i = (blk * 4 + wave) * TPW + tg;
    if (i >= n) break;
    const size_t i16 = (size_t)i * 16;

    for (int s = 0; s < 9; ++s) {
      const int slot = lane + 64*s;
      if (slot < 544) {
        const int row = slot >> 5, k4 = slot & 31;
        const int j = (row < 16) ? knn[i16 + row] : i;
        const float4 p = *(const float4*)(PQ + (size_t)i*256 + k4*4);
        const float4 q = *(const float4*)(PQ + (size_t)j*256 + 128 + k4*4);
        const float t0 = fmaxf(p.x + q.x, 0.f), t1 = fmaxf(p.y + q.y, 0.f);
        const float t2 = fmaxf(p.z + q.z, 0.f), t3 = fmaxf(p.w + q.w, 0.f);
        int2 w;
        w.x = ((int)(unsigned short)f2bf(t1) << 16) | (unsigned short)f2bf(t0);
        w.y = ((int)(unsigned short)f2bf(t3) << 16) | (unsigned short)f2bf(t2);
        *(int2*)&T[row*136 + k4*4] = w;
      }
    }

    f32x4 acc0[4], acc1[4];
#pragma unroll
    for (int nt = 0; nt < 4; ++nt) {
      acc0[nt] = (f32x4)0.f;
      acc1[nt] = (f32x4)0.f;
    }
#pragma unroll
    for (int kt = 0; kt < 4; ++kt) {
      const short8v a1 = *(const short8v*)&T[(lane&15)*136 + kt*32 + (lane>>4)*8];
      const short8v a2 = *(const short8v*)&T[16*136 + kt*32 + (lane>>4)*8];
#pragma unroll
      for (int nt = 0; nt < 4; ++nt) {
        acc0[nt] = __builtin_amdgcn_mfma_f32_16x16x32_bf16(a1, bfr[nt][kt], acc0[nt], 0, 0, 0);
        acc1[nt] = __builtin_amdgcn_mfma_f32_16x16x32_bf16(a2, bfr[nt][kt], acc1[nt], 0, 0, 0);
      }
    }

    float v[4];
#pragma unroll
    for (int nt = 0; nt < 4; ++nt) {
      float m = fmaxf(fmaxf(acc0[nt][0], acc0[nt][1]),
                      fmaxf(acc0[nt][2], acc0[nt][3]));
      m = fmaxf(m, acc1[nt][0]);
      m = fmaxf(m, __shfl_xor(m, 16, 64));
      m = fmaxf(m, __shfl_xor(m, 32, 64));
      v[nt] = m;
    }
    const int g = lane >> 4;
    float r = v[0];
    r = (g == 1) ? v[1] : r;
    r = (g == 2) ? v[2] : r;
    r = (g == 3) ? v[3] : r;
    out[(size_t)i*ldo + lane] = fmaxf(r + b2v, 0.f);
  }
}

// ---------------------------------------------------------------------------
// Mega kernel: [0,KB) knn | [KB,KB+EB) ea permute->bf16 | [KB+EB,+64) pack |
// [KB+EB+64, +MB) R1 = x @ wm1[:,16:]^T  (bf16 MFMA).
// ---------------------------------------------------------------------------
__global__ __launch_bounds__(256) void mega_kernel(
    const float* __restrict__ locs4s, const int* __restrict__ oidx,
    const int* __restrict__ cellstart, int* __restrict__ knn, int n,
    const float* __restrict__ ea, const int* __restrict__ cs_eid,
    short* __restrict__ eac, int E,
    const float* __restrict__ w1A, const float* __restrict__ b1A,
    float* __restrict__ wpqA, float* __restrict__ bpqA,
    const float* __restrict__ w1B, const float* __restrict__ b1B,
    float* __restrict__ wpqB, float* __restrict__ bpqB,
    const float* __restrict__ x, const float* __restrict__ wm1,
    float* __restrict__ Rout,
    int KB, int EB)
{
  __shared__ __align__(16) char smem[4*320*8 + 4*KNN_PCAP*4];  // 35840 B
  const int bid = blockIdx.x;
  if (bid < KB) {
    knn_body(bid, (ull*)smem, (int*)(smem + 4*320*8),
             locs4s, oidx, cellstart, knn, n);
  } else if (bid < KB + EB) {
    const int e = (bid - KB) * 256 + threadIdx.x;
    if (e < E) {
      const float* src = ea + (size_t)cs_eid[e]*16;
      short tmp[16];
#pragma unroll
      for (int u = 0; u < 4; ++u) {
        const float4 v = *(const float4*)(src + u*4);
        tmp[u*4+0] = f2bf(v.x); tmp[u*4+1] = f2bf(v.y);
        tmp[u*4+2] = f2bf(v.z); tmp[u*4+3] = f2bf(v.w);
      }
      *(short8v*)(eac + (size_t)e*16)     = *(short8v*)&tmp[0];
      *(short8v*)(eac + (size_t)e*16 + 8) = *(short8v*)&tmp[8];
    }
  } else if (bid < KB + EB + 64) {
    const int gidx = (bid - KB - EB) * 256 + threadIdx.x;
    const int l = gidx >> 13;
    const int idx = gidx & 8191;
    const float* w1 = l ? w1B : w1A;
    const float* b1 = l ? b1B : b1A;
    float* wpq = l ? wpqB : wpqA;
    float* bpq = l ? bpqB : bpqA;
    const int o = idx >> 6, i = idx & 63;
    const float a = w1[o*128 + i], b = w1[o*128 + 64 + i];
    wpq[idx] = a - b;
    wpq[128*64 + idx] = b;
    if (idx < 128) { bpq[idx] = b1[idx]; bpq[128 + idx] = 0.f; }
  } else {
    // R1 GEMM: Rout = x @ wm1^T  (wm1 pre-offset +16, ld 80)
    short* As = (short*)smem;
    short* Ws = (short*)(smem + 64*72*2);
    const int tid = threadIdx.x;
    const int wave = tid >> 6, lane = tid & 63;
    const int grp = lane >> 4, li = lane & 15;
    const int m0 = (bid - KB - EB - 64) * 64;
    const int srow = tid >> 2;
    const int sc16 = (tid & 3) * 16;
    const int gr = m0 + srow;
    stage_tile_bf16(As, x + (size_t)gr*64 + sc16, srow, sc16, gr < n);
    stage_tile_bf16(Ws, wm1 + (size_t)srow*80 + sc16, srow, sc16, true);
    __syncthreads();
    f32x4 acc[4];
#pragma unroll
    for (int nt = 0; nt < 4; ++nt) acc[nt] = (f32x4)0.f;
#pragma unroll
    for (int ks = 0; ks < 2; ++ks) {
      const short8v a = *(const short8v*)&As[(wave*16 + li)*72 + ks*32 + grp*8];
#pragma unroll
      for (int nt = 0; nt < 4; ++nt) {
        const short8v b = *(const short8v*)&Ws[(nt*16 + li)*72 + ks*32 + grp*8];
        acc[nt] = __builtin_amdgcn_mfma_f32_16x16x32_bf16(a, b, acc[nt], 0, 0, 0);
      }
    }
#pragma unroll
    for (int nt = 0; nt < 4; ++nt) {
      const int ch = nt*16 + li;
#pragma unroll
      for (int j = 0; j < 4; ++j) {
        const int r = m0 + wave*16 + grp*4 + j;
        if (r < n) Rout[(size_t)r*64 + ch] = acc[nt][j];
      }
    }
  }
}

// ---------------------------------------------------------------------------
// Standalone kernels (msg1, dyn1) + combos for independent-stage merging.
// ---------------------------------------------------------------------------
__global__ __launch_bounds__(256) void static_msg_kernel(
    const float* __restrict__ R, const short* __restrict__ eac,
    const float* __restrict__ wm, const float* __restrict__ bm,
    const int* __restrict__ cs_src, const int* __restrict__ rowptr,
    float* __restrict__ agg, int n)
{
  msg_body(blockIdx.x, R, eac, wm, bm, cs_src, rowptr, agg, n);
}

__global__ __launch_bounds__(256) void dyn_mfma_kernel(
    const float* __restrict__ PQ,
    const float* __restrict__ W2, const float* __restrict__ b2,
    const int* __restrict__ knn, float* __restrict__ out, int ldo, int n)
{
  __shared__ __align__(16) char smem[64*136*2 + 4*17*136*2];
  dyn_body((short*)smem, (short*)(smem + 64*136*2), blockIdx.x,
           PQ, W2, b2, knn, out, ldo, n);
}

// combo: msg (blocks [0,SMB)) + linear (blocks [SMB, SMB+MB*4))
__global__ __launch_bounds__(256) void combo_msg_lin_kernel(
    const float* __restrict__ R, const short* __restrict__ eac,
    const float* __restrict__ wm, const float* __restrict__ bm,
    const int* __restrict__ cs_src, const int* __restrict__ rowptr,
    float* __restrict__ agg,
    const float* __restrict__ A, int lda,
    const float* __restrict__ W, int ldw, const float* __restrict__ bias,
    float* __restrict__ C, int ldc, int K, int n, int SMB, int MB)
{
  __shared__ short As[64 * 72];
  __shared__ short Ws[64 * 72];
  const int bid = blockIdx.x;
  if (bid < SMB) {
    msg_body(bid, R, eac, wm, bm, cs_src, rowptr, agg, n);
  } else {
    const int flat = bid - SMB;
    lin_body<false>(As, Ws, flat % MB, flat / MB, A, lda, W, ldw, bias,
                    C, ldc, n, K);
  }
}

// combo: fused_hR (blocks [0,MB)) + dyn conv (blocks [MB, MB+DB))
__global__ __launch_bounds__(256) void combo_hR_dyn_kernel(
    const float* __restrict__ Ain,
    const float* __restrict__ Wu, const float* __restrict__ bu,
    float* __restrict__ Hout, int ldh,
    const float* __restrict__ Wm, float* __restrict__ Rout,
    const float* __restrict__ PQ,
    const float* __restrict__ W2, const float* __restrict__ b2,
    const int* __restrict__ knn, float* __restrict__ outp, int ldo,
    int n, int MB)
{
  __shared__ __align__(16) char smem[64*136*2 + 4*17*136*2];  // 36992 B
  const int bid = blockIdx.x;
  if (bid < MB) {
    hR_body((short*)smem, (short*)(smem + 64*72*2), bid,
            Ain, Wu, bu, Hout, ldh, Wm, Rout, n);
  } else {
    dyn_body((short*)smem, (short*)(smem + 64*136*2), bid - MB,
             PQ, W2, b2, knn, outp, ldo, n);
  }
}

// ---------------------------------------------------------------------------
// Fused output stage (round-16/17 version, verified): h3 in LDS, fu1 in LDS,
// out = [CAT,h3]@f2w[:,64:]^T + fu1@f2w[:,0:64]^T + f2b.
// ---------------------------------------------------------------------------
__global__ __launch_bounds__(256) void fusion_kernel(
    const float* __restrict__ CAT,
    const float* __restrict__ aggv,
    const float* __restrict__ wu3, const float* __restrict__ bu3,
    const float* __restrict__ f1w, const float* __restrict__ f1b,
    const float* __restrict__ f2w, const float* __restrict__ f2bias,
    float* __restrict__ out, int M)
{
  __shared__ short As[64 * 72];
  __shared__ short W1s[64 * 72];
  __shared__ short W2s[64 * 72];
  __shared__ short H3s[64 * 72];
  const int tid = threadIdx.x;
  const int wave = tid >> 6, lane = tid & 63;
  const int grp = lane >> 4, li = lane & 15;
  const int m0 = blockIdx.x * 64;
  const int srow = tid >> 2;
  const int sc16 = (tid & 3) * 16;

  // ---- phase 0: h3 tile ----
  {
    const int gr = m0 + srow;
    stage_tile_bf16(As,  aggv + (size_t)gr*64 + sc16, srow, sc16, gr < M);
    stage_tile_bf16(W1s, wu3 + (size_t)srow*64 + sc16, srow, sc16, true);
  }
  __syncthreads();
  f32x4 acc1[4], acc2[4];
#pragma unroll
  for (int nt = 0; nt < 4; ++nt) { acc1[nt] = (f32x4)0.f; acc2[nt] = (f32x4)0.f; }
#pragma unroll
  for (int ks = 0; ks < 2; ++ks) {
    const short8v a = *(const short8v*)&As[(wave*16 + li)*72 + ks*32 + grp*8];
#pragma unroll
    for (int nt = 0; nt < 4; ++nt) {
      const short8v b = *(const short8v*)&W1s[(nt*16 + li)*72 + ks*32 + grp*8];
      acc1[nt] = __builtin_amdgcn_mfma_f32_16x16x32_bf16(a, b, acc1[nt], 0, 0, 0);
    }
  }
#pragma unroll
  for (int nt = 0; nt < 4; ++nt) {
    const int ch = nt*16 + li;
    const float b = bu3[ch];
#pragma unroll
    for (int j = 0; j < 4; ++j) {
      const int row = wave*16 + grp*4 + j;
      H3s[row*72 + ch] = f2bf(fmaxf(acc1[nt][j] + b, 0.f));
    }
  }
  __syncthreads();

  // ---- main loop: 4 CAT tiles + h3 tile ----
#pragma unroll
  for (int nt = 0; nt < 4; ++nt) acc1[nt] = (f32x4)0.f;
  for (int tile = 0; tile < 5; ++tile) {
    const int kt = tile * 64;
    if (tile < 4) {
      const int gr = m0 + srow;
      stage_tile_bf16(As, CAT + (size_t)gr*320 + kt + sc16, srow, sc16, gr < M);
    }
    stage_tile_bf16(W1s, f1w + (size_t)srow*320 + kt + sc16, srow, sc16, true);
    stage_tile_bf16(W2s, f2w + (size_t)srow*384 + 64 + kt + sc16, srow, sc16, true);
    __syncthreads();
    const short* Ause = (tile < 4) ? As : H3s;
#pragma unroll
    for (int ks = 0; ks < 2; ++ks) {
      const short8v a = *(const short8v*)&Ause[(wave*16 + li)*72 + ks*32 + grp*8];
#pragma unroll
      for (int nt = 0; nt < 4; ++nt) {
        const short8v b1 = *(const short8v*)&W1s[(nt*16 + li)*72 + ks*32 + grp*8];
        const short8v b2 = *(const short8v*)&W2s[(nt*16 + li)*72 + ks*32 + grp*8];
        acc1[nt] = __builtin_amdgcn_mfma_f32_16x16x32_bf16(a, b1, acc1[nt], 0, 0, 0);
        acc2[nt] = __builtin_amdgcn_mfma_f32_16x16x32_bf16(a, b2, acc2[nt], 0, 0, 0);
      }
    }
    __syncthreads();
  }

  // ---- fu1 finish ----
  stage_tile_bf16(W1s, f2w + (size_t)srow*384 + sc16, srow, sc16, true);
#pragma unroll
  for (int nt = 0; nt < 4; ++nt) {
    const int ch = nt*16 + li;
    const float b = f1b[ch];
#pragma unroll
    for (int j = 0; j < 4; ++j) {
      const int row = wave*16 + grp*4 + j;
      As[row*72 + ch] = f2bf(fmaxf(acc1[nt][j] + b, 0.f));
    }
  }
  __syncthreads();
#pragma unroll
  for (int ks = 0; ks < 2; ++ks) {
    const short8v a = *(const short8v*)&As[(wave*16 + li)*72 + ks*32 + grp*8];
#pragma unroll
    for (int nt = 0; nt < 4; ++nt) {
      const short8v b = *(const short8v*)&W1s[(nt*16 + li)*72 + ks*32 + grp*8];
      acc2[nt] = __builtin_amdgcn_mfma_f32_16x16x32_bf16(a, b, acc2[nt], 0, 0, 0);
    }
  }
#pragma unroll
  for (int nt = 0; nt < 4; ++nt) {
    const int ch = nt*16 + li;
    const float b = f2bias[ch];
#pragma unroll
    for (int j = 0; j < 4; ++j) {
      const int gr = m0 + wave*16 + grp*4 + j;
      if (gr < M) out[(size_t)gr*64 + ch] = acc2[nt][j] + b;
    }
  }
}

// ---------------------------------------------------------------------------
// Host orchestration
// ---------------------------------------------------------------------------
extern "C" void kernel_launch(void* const* d_in, const int* in_sizes, int n_in,
                              void* d_out, int out_size, void* d_ws, size_t ws_size,
                              hipStream_t stream)
{
  const float* x   = (const float*)d_in[0];
  const int*   ei  = (const int*)d_in[1];
  const float* ea  = (const float*)d_in[2];
  const float* loc = (const float*)d_in[3];
  const float* sg_wm[3] = {(const float*)d_in[5],  (const float*)d_in[9],  (const float*)d_in[13]};
  const float* sg_bm[3] = {(const float*)d_in[6],  (const float*)d_in[10], (const float*)d_in[14]};
  const float* sg_wu[3] = {(const float*)d_in[7],  (const float*)d_in[11], (const float*)d_in[15]};
  const float* sg_bu[3] = {(const float*)d_in[8],  (const float*)d_in[12], (const float*)d_in[16]};
  const float* dg_w1[2] = {(const float*)d_in[17], (const float*)d_in[21]};
  const float* dg_b1[2] = {(const float*)d_in[18], (const float*)d_in[22]};
  const float* dg_w2[2] = {(const float*)d_in[19], (const float*)d_in[23]};
  const float* dg_b2[2] = {(const float*)d_in[20], (const float*)d_in[24]};
  const float* f1_w = (const float*)d_in[25];
  const float* f1_b = (const float*)d_in[26];
  const float* f2_w = (const float*)d_in[27];
  const float* f2_b = (const float*)d_in[28];
  float* out = (float*)d_out;

  const int n    = in_sizes[0] / 64;
  const int Etot = in_sizes[1] / 2;
  const int* srcp = ei;
  const int* dstp = ei + Etot;

  char* basep = (char*)d_ws;
  size_t cur = 0;
  auto alloc = [&](size_t bytes) -> void* {
    void* p = basep + cur;
    cur = (cur + bytes + 255) & ~(size_t)255;
    return p;
  };
  float* CAT  = (float*)alloc((size_t)n * 320 * 4);   // cols 256.. unused
  float* Rb   = (float*)alloc((size_t)n * 64 * 4);
  float* PQb  = (float*)alloc((size_t)n * 256 * 4);
  float* agg  = (float*)alloc((size_t)n * 64 * 4);
  float* wpq[2];
  float* bpq[2];
  wpq[0] = (float*)alloc(256 * 64 * 4);  bpq[0] = (float*)alloc(256 * 4);
  wpq[1] = (float*)alloc(256 * 64 * 4);  bpq[1] = (float*)alloc(256 * 4);
  int* knnb   = (int*)alloc((size_t)n * 16 * 4);
  int* zeros     = (int*)alloc((size_t)(2*KNN_NC + 2*n) * 4);
  int* cellcount = zeros;
  int* cellfill  = zeros + KNN_NC;
  int* deg       = zeros + 2*KNN_NC;
  int* dfill     = zeros + 2*KNN_NC + n;
  int* cellstart = (int*)alloc((size_t)(KNN_NC + 1) * 4);
  int* cellidb   = (int*)alloc((size_t)n * 4);
  float* locs4s  = (float*)alloc((size_t)n * 4 * 4);
  int* oidx      = (int*)alloc((size_t)n * 4);
  int* rowptr    = (int*)alloc((size_t)(n + 1) * 4);
  int* cs_src    = (int*)alloc((size_t)Etot * 4);
  int* cs_eid    = (int*)alloc((size_t)Etot * 4);
  short* ea_csr  = (short*)alloc((size_t)Etot * 16 * 2);   // bf16
  (void)ws_size; (void)n_in; (void)out_size;

  const int nbE = (Etot + 255) / 256;
  const int mb = (n + 63) / 64;
  const int smb = (n + 4*TPW_S - 1) / (4*TPW_S);
  const int db = (n + 4*TPW - 1) / (4*TPW);

  hipMemsetAsync(zeros, 0, (size_t)(2*KNN_NC + 2*n) * 4, stream);
  count2_kernel<<<nbE, 256, 0, stream>>>(loc, cellcount, cellidb, n,
                                         dstp, deg, Etot);
  scan2_kernel<<<2, 1024, 0, stream>>>(cellcount, cellstart, KNN_NC,
                                       (KNN_NC + 1023) / 1024,
                                       deg, rowptr, n, (n + 1023) / 1024);
  scatter2_kernel<<<nbE, 256, 0, stream>>>(loc, cellidb, cellstart, cellfill,
                                           locs4s, oidx, n,
                                           srcp, dstp, rowptr, dfill,
                                           cs_src, cs_eid, Etot);
  const int KB = (n + 3) / 4;
  const int EB = (Etot + 255) / 256;      // one edge per thread
  mega_kernel<<<KB + EB + 64 + mb, 256, 0, stream>>>(
      locs4s, oidx, cellstart, knnb, n,
      ea, cs_eid, ea_csr, Etot,
      dg_w1[0], dg_b1[0], wpq[0], bpq[0],
      dg_w1[1], dg_b1[1], wpq[1], bpq[1],
      x, sg_wm[0] + 16, Rb,
      KB, EB);

  // msg1: Rb -> agg
  static_msg_kernel<<<smb, 256, 0, stream>>>(Rb, ea_csr, sg_wm[0], sg_bm[0],
                                             cs_src, rowptr, agg, n);
  // hR1: agg -> h1(CAT+0), R2(Rb)   [standalone: nothing independent yet]
  {
    __attribute__((unused)) int dummy = 0;
  }
  combo_hR_dyn_kernel<<<mb, 256, 0, stream>>>(
      agg, sg_wu[0], sg_bu[0], CAT + 0, 320, sg_wm[1] + 16, Rb,
      nullptr, nullptr, nullptr, nullptr, nullptr, 0, n, mb);  // hR-only grid

  // combo1: msg2 (Rb->agg) + PQlin0 (CAT+0 -> PQb)
  combo_msg_lin_kernel<<<smb + mb*4, 256, 0, stream>>>(
      Rb, ea_csr, sg_wm[1], sg_bm[1], cs_src, rowptr, agg,
      CAT + 0, 320, wpq[0], 64, bpq[0], PQb, 256, 64, n, smb, mb);

  // combo2: hR2 (agg -> h2(CAT+192), R3(Rb)) + dyn0 (PQb -> g1(CAT+64))
  combo_hR_dyn_kernel<<<mb + db, 256, 0, stream>>>(
      agg, sg_wu[1], sg_bu[1], CAT + 192, 320, sg_wm[2] + 16, Rb,
      PQb, dg_w2[0], dg_b2[0], knnb, CAT + 64, 320, n, mb);

  // combo3: msg3 (Rb->agg) + PQlin1 (g1 -> PQb)
  combo_msg_lin_kernel<<<smb + mb*4, 256, 0, stream>>>(
      Rb, ea_csr, sg_wm[2], sg_bm[2], cs_src, rowptr, agg,
      CAT + 64, 320, wpq[1], 64, bpq[1], PQb, 256, 64, n, smb, mb);

  // dyn1: PQb -> g2(CAT+128)
  dyn_mfma_kernel<<<db, 256, 0, stream>>>(PQb, dg_w2[1], dg_b2[1],
                                          knnb, CAT + 128, 320, n);

  // fused output stage (includes h3 from agg)
  fusion_kernel<<<mb, 256, 0, stream>>>(CAT, agg, sg_wu[2], sg_bu[2],
                                        f1_w, f1_b, f2_w, f2_b, out, n);
}

// Round 21
// 278.968 us; speedup vs baseline: 1.7912x; 1.0043x over previous
//
#include <hip/hip_runtime.h>

#define INF_F __builtin_inff()

typedef __attribute__((ext_vector_type(8))) short short8v;  // 8 bf16
typedef __attribute__((ext_vector_type(4))) float f32x4;
typedef unsigned long long ull;
typedef unsigned short u16;

__device__ __forceinline__ short f2bf(float x) {
  const unsigned u = __float_as_uint(x);
  return (short)((u + 0x7FFFu + ((u >> 16) & 1u)) >> 16);   // RNE
}

__device__ __forceinline__ unsigned mbcnt64(ull m) {
  return __builtin_amdgcn_mbcnt_hi((unsigned)(m >> 32),
                                   __builtin_amdgcn_mbcnt_lo((unsigned)m, 0u));
}

// ===========================================================================
// Spatial-bin exact kNN, WAVE-per-target, G=5, materialized flat position
// list stored as u16 (positions < n = 10000 < 65536) -> LDS 23.0 KB/block
// (was 35.8), 6 blocks/CU instead of 4 for the latency-bound scan.
// ===========================================================================
#define KNN_G 5
#define KNN_NC (KNN_G*KNN_G*KNN_G*KNN_G)   // 625
#define KNN_PCAP 1600

// ---- merged init kernels ---------------------------------------------------
__global__ __launch_bounds__(256) void count2_kernel(
    const float* __restrict__ loc, int* __restrict__ cellcount,
    int* __restrict__ cellid, int n,
    const int* __restrict__ dst, int* __restrict__ deg, int E)
{
  const int i = blockIdx.x * 256 + threadIdx.x;
  if (i < n) {
    const float4 l = *(const float4*)(loc + (size_t)i*4);
    const int cx = min(KNN_G-1, (int)(l.x * (float)KNN_G));
    const int cy = min(KNN_G-1, (int)(l.y * (float)KNN_G));
    const int cz = min(KNN_G-1, (int)(l.z * (float)KNN_G));
    const int cw = min(KNN_G-1, (int)(l.w * (float)KNN_G));
    const int c = ((cx*KNN_G + cy)*KNN_G + cz)*KNN_G + cw;
    cellid[i] = c;
    atomicAdd(&cellcount[c], 1);
  }
  if (i < E) atomicAdd(&deg[dst[i]], 1);
}

__device__ __forceinline__ void scan1b_body(
    const int* __restrict__ in, int* __restrict__ out, int n, int per)
{
  __shared__ int part[1024];
  const int t = threadIdx.x;
  const int lo = t * per, hi = min(lo + per, n);
  int sum = 0;
  for (int idx = lo; idx < hi; ++idx) sum += in[idx];
  int v = sum;
  part[t] = v;
  __syncthreads();
  for (int off = 1; off < 1024; off <<= 1) {
    const int o = (t >= off) ? part[t - off] : 0;
    __syncthreads();
    v += o;
    part[t] = v;
    __syncthreads();
  }
  int run = v - sum;
  for (int idx = lo; idx < hi; ++idx) { out[idx] = run; run += in[idx]; }
  if (t == 1023) out[n] = v;
}

__global__ __launch_bounds__(1024) void scan2_kernel(
    const int* __restrict__ inA, int* __restrict__ outA, int nA, int perA,
    const int* __restrict__ inB, int* __restrict__ outB, int nB, int perB)
{
  if (blockIdx.x == 0) scan1b_body(inA, outA, nA, perA);
  else                 scan1b_body(inB, outB, nB, perB);
}

__global__ __launch_bounds__(256) void scatter2_kernel(
    const float* __restrict__ loc, const int* __restrict__ cellid,
    const int* __restrict__ cellstart, int* __restrict__ cellfill,
    float* __restrict__ locs4s, int* __restrict__ oidx, int n,
    const int* __restrict__ srcs, const int* __restrict__ dsts,
    const int* __restrict__ rowptr, int* __restrict__ dfill,
    int* __restrict__ cs_src, int* __restrict__ cs_eid, int E)
{
  const int i = blockIdx.x * 256 + threadIdx.x;
  if (i < n) {
    const int c = cellid[i];
    const int pos = cellstart[c] + atomicAdd(&cellfill[c], 1);
    *(float4*)(locs4s + (size_t)pos*4) = *(const float4*)(loc + (size_t)i*4);
    oidx[pos] = i;
  }
  if (i < E) {
    const int d = dsts[i];
    const int pos = rowptr[d] + atomicAdd(&dfill[d], 1);
    cs_src[pos] = srcs[i];
    cs_eid[pos] = i;
  }
}

// ---- kNN selection helpers -------------------------------------------------
__device__ __forceinline__ ull
knn_refine16(ull* __restrict__ B, int cnt, int lane, ull& topsave)
{
  ull v[5];
#pragma unroll
  for (int s = 0; s < 5; ++s) {
    const int idx = lane + 64*s;
    v[s] = (idx < cnt) ? B[idx] : ~0ull;
  }
  ull tau = ~0ull;
#pragma unroll
  for (int r = 0; r < 16; ++r) {
    ull m = v[0]; int sl = 0;
#pragma unroll
    for (int s = 1; s < 5; ++s) if (v[s] < m) { m = v[s]; sl = s; }
    ull mm = m;
#pragma unroll
    for (int off = 32; off >= 1; off >>= 1) {
      const ull o = __shfl_xor(mm, off, 64);
      if (o < mm) mm = o;
    }
    const bool killer = (m == mm);
#pragma unroll
    for (int s = 0; s < 5; ++s) if (killer && sl == s) v[s] = ~0ull;
    if (lane == r) topsave = mm;
    tau = mm;            // after round 15: exact 16th-smallest
  }
  if (lane < 16) B[lane] = topsave;
  return tau;
}

__device__ __forceinline__ int
knn_filter(ull* __restrict__ B, int cnt, int lane, ull& tau)
{
  ull v[5];
#pragma unroll
  for (int s = 0; s < 5; ++s) {
    const int idx = lane + 64*s;
    v[s] = (idx < cnt) ? B[idx] : ~0ull;
  }
  ull g = v[0];
#pragma unroll
  for (int s = 1; s < 5; ++s) if (v[s] < g) g = v[s];
  { ull o = __shfl_xor(g, 1, 64); if (o < g) g = o;
    o = __shfl_xor(g, 2, 64); if (o < g) g = o; }
  ull t = g;
#pragma unroll
  for (int off = 4; off <= 32; off <<= 1) {
    const ull o = __shfl_xor(t, off, 64);
    if (o > t) t = o;
  }
  int nc = 0;
#pragma unroll
  for (int s = 0; s < 5; ++s) {
    const bool keep = (v[s] <= t) && (v[s] != ~0ull);
    const ull mask = __ballot(keep);
    if (mask) {
      const unsigned pre = mbcnt64(mask);
      if (keep) B[nc + pre] = v[s];
      nc += (int)__popcll(mask);
    }
  }
  tau = t;
  return nc;
}

__device__ void knn_body(int blk, ull* __restrict__ Bs, u16* __restrict__ PosAll,
                         const float* __restrict__ locs4s,
                         const int* __restrict__ oidx,
                         const int* __restrict__ cellstart,
                         int* __restrict__ knn, int n)
{
#pragma clang fp contract(off)
  constexpr int TRIG = 256;
  const int wave = threadIdx.x >> 6, lane = threadIdx.x & 63;
  const int t = blk * 4 + wave;          // sorted position of target
  if (t >= n) return;                    // wave-uniform exit
  ull* B = Bs + wave * 320;
  u16* Pos = PosAll + wave * KNN_PCAP;

  const float4 L = *(const float4*)(locs4s + (size_t)t*4);
  const float tx = L.x, ty = L.y, tz = L.z, tw = L.w;
  const int cx = min(KNN_G-1, (int)(tx * (float)KNN_G));
  const int cy = min(KNN_G-1, (int)(ty * (float)KNN_G));
  const int cz = min(KNN_G-1, (int)(tz * (float)KNN_G));
  const int cw = min(KNN_G-1, (int)(tw * (float)KNN_G));

  ull tau = ~0ull;
  ull topsave = ~0ull;
  int cnt = 0;

  auto boundB = [&](int mr) -> float {
    const float w = 1.0f / (float)KNN_G;
    float Bv = INF_F;
    if (cx - mr >= 1)         Bv = fminf(Bv, tx - (float)(cx - mr) * w);
    if (cx + mr <= KNN_G - 2) Bv = fminf(Bv, (float)(cx + mr + 1) * w - tx);
    if (cy - mr >= 1)         Bv = fminf(Bv, ty - (float)(cy - mr) * w);
    if (cy + mr <= KNN_G - 2) Bv = fminf(Bv, (float)(cy + mr + 1) * w - ty);
    if (cz - mr >= 1)         Bv = fminf(Bv, tz - (float)(cz - mr) * w);
    if (cz + mr <= KNN_G - 2) Bv = fminf(Bv, (float)(cz + mr + 1) * w - tz);
    if (cw - mr >= 1)         Bv = fminf(Bv, tw - (float)(cw - mr) * w);
    if (cw + mr <= KNN_G - 2) Bv = fminf(Bv, (float)(cw + mr + 1) * w - tw);
    return Bv;
  };

  auto do_range = [&](int ps, int pe) {
    for (int p0 = ps; p0 < pe; p0 += 64) {
      const int p = p0 + lane;
      ull key = ~0ull;
      if (p < pe && p != t) {
        const float4 q = *(const float4*)(locs4s + (size_t)p*4);
        const int oj = oidx[p];
        const float a0 = q.x - tx, a1 = q.y - ty, a2 = q.z - tz, a3 = q.w - tw;
        const float s0 = a0*a0, s1 = a1*a1, s2 = a2*a2, s3 = a3*a3;
        const float d = ((s0 + s1) + s2) + s3;
        key = ((ull)__float_as_uint(d) << 32) | (unsigned)oj;
      }
      const bool surv = key < tau;
      const ull mask = __ballot(surv);
      if (mask) {
        const unsigned pre = mbcnt64(mask);
        if (surv) B[cnt + pre] = key;
        cnt += (int)__popcll(mask);
        if (cnt > TRIG) cnt = knn_filter(B, cnt, lane, tau);
      }
    }
  };

  // ---- level 0: radius-1 block as a materialized flat position list ----
  int psv = 0, pev = 0;
  if (lane < 27) {
    const int cr = (lane == 0) ? 13 : (lane <= 13 ? lane - 1 : lane);
    const int ax = cx + (cr / 9) - 1;
    const int ay = cy + ((cr / 3) % 3) - 1;
    const int az = cz + (cr % 3) - 1;
    if (ax >= 0 && ax < KNN_G && ay >= 0 && ay < KNN_G &&
        az >= 0 && az < KNN_G) {
      const int base = ((ax*KNN_G + ay)*KNN_G + az)*KNN_G;
      const int wlo = max(cw-1, 0), whi = min(cw+1, KNN_G-1);
      psv = cellstart[base + wlo];
      pev = cellstart[base + whi + 1];
    }
  }
  const int len = max(pev - psv, 0);
  int cum = len;
#pragma unroll
  for (int off = 1; off < 64; off <<= 1) {
    const int o = __shfl_up(cum, off, 64);
    if (lane >= off) cum += o;
  }
  const int T = __shfl(cum, 63, 64);
  const int startv = cum - len;

  for (int p = psv, f = startv; p < pev && f < KNN_PCAP; ++p, ++f)
    Pos[f] = (u16)p;

  const int Tb = min(T, KNN_PCAP);
  const int Tm1b = Tb - 1;
  float4 qn; int ojn = 0, pgn = 0; bool vn = false;
  {
    vn = lane < Tb;
    pgn = Pos[min(lane, Tm1b)];
    qn = *(const float4*)(locs4s + (size_t)pgn*4);
    ojn = oidx[pgn];
  }
  for (int f0 = 0; f0 < Tb; f0 += 64) {
    const float4 qc = qn; const int ojc = ojn, pgc = pgn; const bool vc = vn;
    const int fN = f0 + 64 + lane;
    vn = fN < Tb;
    if (f0 + 64 < Tb) {
      pgn = Pos[min(fN, Tm1b)];
      qn = *(const float4*)(locs4s + (size_t)pgn*4);
      ojn = oidx[pgn];
    }
    ull key = ~0ull;
    if (vc && pgc != t) {
      const float a0 = qc.x - tx, a1 = qc.y - ty, a2 = qc.z - tz, a3 = qc.w - tw;
      const float s0 = a0*a0, s1 = a1*a1, s2 = a2*a2, s3 = a3*a3;
      const float d = ((s0 + s1) + s2) + s3;
      key = ((ull)__float_as_uint(d) << 32) | (unsigned)ojc;
    }
    const bool surv = key < tau;
    const ull mask = __ballot(surv);
    if (mask) {
      const unsigned pre = mbcnt64(mask);
      if (surv) B[cnt + pre] = key;
      cnt += (int)__popcll(mask);
      if (cnt > TRIG) cnt = knn_filter(B, cnt, lane, tau);
    }
  }
  if (T > KNN_PCAP) {
    for (int r = 0; r < 27; ++r) {
      const int st = __shfl(startv, r, 64);
      const int ps = __shfl(psv, r, 64);
      const int pe = __shfl(pev, r, 64);
      const int done = min(max(KNN_PCAP - st, 0), pe - ps);
      if (ps + done < pe) do_range(ps + done, pe);
    }
  }

  // ---- shells m = 2..G-1 (rare; exact refine + per-target bound check) ----
  for (int m = 2; m <= KNN_G - 1; ++m) {
    if (cnt > 16) { tau = knn_refine16(B, cnt, lane, topsave); cnt = 16; }
    if (tau != ~0ull) {
      const float taud = __uint_as_float((unsigned)(tau >> 32));
      const float Bv = boundB(m - 1);
      if (Bv == INF_F || taud < Bv * Bv * 0.99999f) break;
    }
    const int xlo = max(cx-m, 0), xhi = min(cx+m, KNN_G-1);
    for (int ax = xlo; ax <= xhi; ++ax) {
      const bool xe = (ax == cx-m) || (ax == cx+m);
      const int ylo = max(cy-m, 0), yhi = min(cy+m, KNN_G-1);
      for (int ay = ylo; ay <= yhi; ++ay) {
        const bool ye = (ay == cy-m) || (ay == cy+m);
        const int zlo = max(cz-m, 0), zhi = min(cz+m, KNN_G-1);
        for (int az = zlo; az <= zhi; ++az) {
          const bool ze = (az == cz-m) || (az == cz+m);
          const int base = ((ax*KNN_G + ay)*KNN_G + az)*KNN_G;
          if (xe | ye | ze) {
            const int wlo = max(cw-m, 0), whi = min(cw+m, KNN_G-1);
            do_range(cellstart[base+wlo], cellstart[base+whi+1]);
          } else {
            if (cw-m >= 0) {
              const int c = base + cw - m;
              do_range(cellstart[c], cellstart[c+1]);
            }
            if (cw+m <= KNN_G-1) {
              const int c = base + cw + m;
              do_range(cellstart[c], cellstart[c+1]);
            }
          }
        }
      }
    }
  }
  (void)knn_refine16(B, cnt, lane, topsave);   // exact top-16
  const int i = oidx[t];
  if (lane < 16) knn[(size_t)i*16 + lane] = (int)(topsave & 0xFFFFFFFFull);
}

// ---------------------------------------------------------------------------
// Staging helper: convert a 64x64 fp32 tile row-chunk to bf16 LDS (pitch 72).
// ---------------------------------------------------------------------------
__device__ __forceinline__ void stage_tile_bf16(
    short* __restrict__ S, const float* __restrict__ src, int srow, int sc16,
    bool valid)
{
  short tmp[16];
  if (valid) {
#pragma unroll
    for (int u = 0; u < 4; ++u) {
      const float4 v = *(const float4*)(src + u*4);
      tmp[u*4+0] = f2bf(v.x); tmp[u*4+1] = f2bf(v.y);
      tmp[u*4+2] = f2bf(v.z); tmp[u*4+3] = f2bf(v.w);
    }
  } else {
#pragma unroll
    for (int u = 0; u < 16; ++u) tmp[u] = 0;
  }
  *(short8v*)&S[srow*72 + sc16]     = *(short8v*)&tmp[0];
  *(short8v*)&S[srow*72 + sc16 + 8] = *(short8v*)&tmp[8];
}

// ---------------------------------------------------------------------------
// Msg body (static conv message + segment max, 2 dsts per wave).
// ---------------------------------------------------------------------------
#define TPW_S 2

__device__ __forceinline__ void msg_body(
    int blk,
    const float* __restrict__ R, const short* __restrict__ eac,
    const float* __restrict__ wm, const float* __restrict__ bm,
    const int* __restrict__ cs_src, const int* __restrict__ rowptr,
    float* __restrict__ agg, int n)
{
  const int wave = threadIdx.x >> 6, lane = threadIdx.x & 63;
  const int grp = lane >> 4, li = lane & 15;

  short8v bfr[4];
  float bmv[4];
#pragma unroll
  for (int nt = 0; nt < 4; ++nt) {
    short8v b = (short8v)0;
    if (grp < 2) {
      const int ch = nt*16 + li;
#pragma unroll
      for (int j = 0; j < 8; ++j) b[j] = f2bf(wm[ch*80 + grp*8 + j]);
    }
    bfr[nt] = b;
    bmv[nt] = bm[nt*16 + li];
  }
  const f32x4 zero = (f32x4)0.f;

  for (int tg = 0; tg < TPW_S; ++tg) {
    const int d = (blk * 4 + wave) * TPW_S + tg;
    if (d >= n) break;                        // wave-uniform
    const int beg = rowptr[d], end = rowptr[d+1];
    const int deg = end - beg;
    float basev[4];
#pragma unroll
    for (int nt = 0; nt < 4; ++nt)
      basev[nt] = bmv[nt] - R[(size_t)d*64 + nt*16 + li];

    float vmax[4] = {0.f, 0.f, 0.f, 0.f};
    for (int m0 = 0; m0 < deg; m0 += 16) {
      short8v a = (short8v)0;
      const int erow = m0 + li;
      if (grp < 2 && erow < deg)
        a = *(const short8v*)(eac + (size_t)(beg + erow)*16 + grp*8);
      f32x4 Dv[4];
#pragma unroll
      for (int nt = 0; nt < 4; ++nt)
        Dv[nt] = __builtin_amdgcn_mfma_f32_16x16x32_bf16(a, bfr[nt], zero, 0, 0, 0);
#pragma unroll
      for (int j = 0; j < 4; ++j) {
        const int m = m0 + grp*4 + j;
        if (m < deg) {
          const int s = cs_src[beg + m];
          const float* Rs = R + (size_t)s*64;
#pragma unroll
          for (int nt = 0; nt < 4; ++nt) {
            const float acc = Dv[nt][j] + Rs[nt*16 + li] + basev[nt];
            vmax[nt] = fmaxf(vmax[nt], fmaxf(acc, 0.f));
          }
        }
      }
    }
#pragma unroll
    for (int nt = 0; nt < 4; ++nt) {
      float m = vmax[nt];
      m = fmaxf(m, __shfl_xor(m, 16, 64));
      m = fmaxf(m, __shfl_xor(m, 32, 64));
      vmax[nt] = m;
    }
    float r = vmax[0];
    r = (grp == 1) ? vmax[1] : r;
    r = (grp == 2) ? vmax[2] : r;
    r = (grp == 3) ? vmax[3] : r;
    agg[(size_t)d*64 + lane] = r;
  }
}

// ---------------------------------------------------------------------------
// Linear body (bf16 MFMA) on caller-carved LDS.
// ---------------------------------------------------------------------------
template<bool RELU>
__device__ __forceinline__ void lin_body(
    short* __restrict__ As, short* __restrict__ Ws,
    int bx, int by,
    const float* __restrict__ A, int lda,
    const float* __restrict__ W, int ldw,
    const float* __restrict__ bias,
    float* __restrict__ C, int ldc, int M, int K)
{
  const int tid = threadIdx.x;
  const int wave = tid >> 6, lane = tid & 63;
  const int grp = lane >> 4, li = lane & 15;
  const int m0 = bx * 64;
  const int c0 = by * 64;

  f32x4 acc[4];
#pragma unroll
  for (int nt = 0; nt < 4; ++nt) acc[nt] = (f32x4)0.f;

  const int srow = tid >> 2;
  const int sc16 = (tid & 3) * 16;

  for (int kt = 0; kt < K; kt += 64) {
    const int gr = m0 + srow;
    stage_tile_bf16(As, A + (size_t)gr*lda + kt + sc16, srow, sc16, gr < M);
    stage_tile_bf16(Ws, W + (size_t)(c0 + srow)*ldw + kt + sc16, srow, sc16, true);
    __syncthreads();
#pragma unroll
    for (int ks = 0; ks < 2; ++ks) {
      const short8v a = *(const short8v*)&As[(wave*16 + li)*72 + ks*32 + grp*8];
#pragma unroll
      for (int nt = 0; nt < 4; ++nt) {
        const short8v b = *(const short8v*)&Ws[(nt*16 + li)*72 + ks*32 + grp*8];
        acc[nt] = __builtin_amdgcn_mfma_f32_16x16x32_bf16(a, b, acc[nt], 0, 0, 0);
      }
    }
    __syncthreads();
  }

#pragma unroll
  for (int nt = 0; nt < 4; ++nt) {
    const int ch = c0 + nt*16 + li;
    const float b = bias ? bias[ch] : 0.f;
#pragma unroll
    for (int j = 0; j < 4; ++j) {
      const int gr = m0 + wave*16 + grp*4 + j;
      if (gr < M) {
        float v = acc[nt][j] + b;
        if (RELU) v = fmaxf(v, 0.f);
        C[(size_t)gr*ldc + ch] = v;
      }
    }
  }
}

// ---------------------------------------------------------------------------
// fused_hR body on caller-carved LDS.
// ---------------------------------------------------------------------------
__device__ __forceinline__ void hR_body(
    short* __restrict__ As, short* __restrict__ Ws, int bx,
    const float* __restrict__ A,
    const float* __restrict__ Wu, const float* __restrict__ bu,
    float* __restrict__ Hout, int ldh,
    const float* __restrict__ Wm,                 // pre-offset +16, ld 80
    float* __restrict__ Rout, int M)
{
  const int tid = threadIdx.x;
  const int wave = tid >> 6, lane = tid & 63;
  const int grp = lane >> 4, li = lane & 15;
  const int m0 = bx * 64;
  const int srow = tid >> 2;
  const int sc16 = (tid & 3) * 16;

  {
    const int gr = m0 + srow;
    stage_tile_bf16(As, A + (size_t)gr*64 + sc16, srow, sc16, gr < M);
    stage_tile_bf16(Ws, Wu + (size_t)srow*64 + sc16, srow, sc16, true);
  }
  __syncthreads();
  f32x4 acc[4];
#pragma unroll
  for (int nt = 0; nt < 4; ++nt) acc[nt] = (f32x4)0.f;
#pragma unroll
  for (int ks = 0; ks < 2; ++ks) {
    const short8v a = *(const short8v*)&As[(wave*16 + li)*72 + ks*32 + grp*8];
#pragma unroll
    for (int nt = 0; nt < 4; ++nt) {
      const short8v b = *(const short8v*)&Ws[(nt*16 + li)*72 + ks*32 + grp*8];
      acc[nt] = __builtin_amdgcn_mfma_f32_16x16x32_bf16(a, b, acc[nt], 0, 0, 0);
    }
  }
  __syncthreads();

  stage_tile_bf16(Ws, Wm + (size_t)srow*80 + sc16, srow, sc16, true);
#pragma unroll
  for (int nt = 0; nt < 4; ++nt) {
    const int ch = nt*16 + li;
    const float b = bu[ch];
#pragma unroll
    for (int j = 0; j < 4; ++j) {
      const int row = wave*16 + grp*4 + j;
      const int gr = m0 + row;
      const float v = fmaxf(acc[nt][j] + b, 0.f);
      if (gr < M) Hout[(size_t)gr*ldh + ch] = v;
      As[row*72 + ch] = f2bf(v);
    }
  }
  __syncthreads();

  f32x4 acc2[4];
#pragma unroll
  for (int nt = 0; nt < 4; ++nt) acc2[nt] = (f32x4)0.f;
#pragma unroll
  for (int ks = 0; ks < 2; ++ks) {
    const short8v a = *(const short8v*)&As[(wave*16 + li)*72 + ks*32 + grp*8];
#pragma unroll
    for (int nt = 0; nt < 4; ++nt) {
      const short8v b = *(const short8v*)&Ws[(nt*16 + li)*72 + ks*32 + grp*8];
      acc2[nt] = __builtin_amdgcn_mfma_f32_16x16x32_bf16(a, b, acc2[nt], 0, 0, 0);
    }
  }
#pragma unroll
  for (int nt = 0; nt < 4; ++nt) {
    const int ch = nt*16 + li;
#pragma unroll
    for (int j = 0; j < 4; ++j) {
      const int gr = m0 + wave*16 + grp*4 + j;
      if (gr < M) Rout[(size_t)gr*64 + ch] = acc2[nt][j];
    }
  }
}

// ---------------------------------------------------------------------------
// dyn conv body on caller-carved LDS.
// ---------------------------------------------------------------------------
#define TPW 4   // targets per wave

__device__ __forceinline__ void dyn_body(
    short* __restrict__ w2s, short* __restrict__ TsAll, int blk,
    const float* __restrict__ PQ,
    const float* __restrict__ W2, const float* __restrict__ b2,
    const int* __restrict__ knn, float* __restrict__ out, int ldo, int n)
{
  const int tid = threadIdx.x;
  const int wave = tid >> 6, lane = tid & 63;

  for (int idx = tid; idx < 64 * 128; idx += 256) {
    const int c = idx >> 7, k = idx & 127;
    w2s[c*136 + k] = f2bf(W2[c*128 + k]);
  }
  __syncthreads();

  short8v bfr[4][4];
#pragma unroll
  for (int nt = 0; nt < 4; ++nt)
#pragma unroll
    for (int kt = 0; kt < 4; ++kt)
      bfr[nt][kt] = *(const short8v*)&w2s[(nt*16 + (lane&15))*136 +
                                          kt*32 + (lane>>4)*8];
  const float b2v = b2[lane];
  short* T = TsAll + wave * (17*136);

  for (int tg = 0; tg < TPW; ++tg) {
    const int i = (blk * 4 + wave) * TPW + tg;
    if (i >= n) break;
    const size_t i16 = (size_t)i * 16;

    for (int s = 0; s < 9; ++s) {
      const int slot = lane + 64*s;
      if (slot < 544) {
        const int row = slot >> 5, k4 = slot & 31;
        const int j = (row < 16) ? knn[i16 + row] : i;
        const float4 p = *(const float4*)(PQ + (size_t)i*256 + k4*4);
        const float4 q = *(const float4*)(PQ + (size_t)j*256 + 128 + k4*4);
        const float t0 = fmaxf(p.x + q.x, 0.f), t1 = fmaxf(p.y + q.y, 0.f);
        const float t2 = fmaxf(p.z + q.z, 0.f), t3 = fmaxf(p.w + q.w, 0.f);
        int2 w;
        w.x = ((int)(unsigned short)f2bf(t1) << 16) | (unsigned short)f2bf(t0);
        w.y = ((int)(unsigned short)f2bf(t3) << 16) | (unsigned short)f2bf(t2);
        *(int2*)&T[row*136 + k4*4] = w;
      }
    }

    f32x4 acc0[4], acc1[4];
#pragma unroll
    for (int nt = 0; nt < 4; ++nt) {
      acc0[nt] = (f32x4)0.f;
      acc1[nt] = (f32x4)0.f;
    }
#pragma unroll
    for (int kt = 0; kt < 4; ++kt) {
      const short8v a1 = *(const short8v*)&T[(lane&15)*136 + kt*32 + (lane>>4)*8];
      const short8v a2 = *(const short8v*)&T[16*136 + kt*32 + (lane>>4)*8];
#pragma unroll
      for (int nt = 0; nt < 4; ++nt) {
        acc0[nt] = __builtin_amdgcn_mfma_f32_16x16x32_bf16(a1, bfr[nt][kt], acc0[nt], 0, 0, 0);
        acc1[nt] = __builtin_amdgcn_mfma_f32_16x16x32_bf16(a2, bfr[nt][kt], acc1[nt], 0, 0, 0);
      }
    }

    float v[4];
#pragma unroll
    for (int nt = 0; nt < 4; ++nt) {
      float m = fmaxf(fmaxf(acc0[nt][0], acc0[nt][1]),
                      fmaxf(acc0[nt][2], acc0[nt][3]));
      m = fmaxf(m, acc1[nt][0]);
      m = fmaxf(m, __shfl_xor(m, 16, 64));
      m = fmaxf(m, __shfl_xor(m, 32, 64));
      v[nt] = m;
    }
    const int g = lane >> 4;
    float r = v[0];
    r = (g == 1) ? v[1] : r;
    r = (g == 2) ? v[2] : r;
    r = (g == 3) ? v[3] : r;
    out[(size_t)i*ldo + lane] = fmaxf(r + b2v, 0.f);
  }
}

// ---------------------------------------------------------------------------
// Mega kernel: [0,KB) knn | [KB,KB+EB) ea permute->bf16 | [KB+EB,+64) pack |
// [KB+EB+64, +MB) R1 = x @ wm1[:,16:]^T  (bf16 MFMA).
// knn LDS: Bs 10240 B + Pos(u16) 12800 B = 23040 B -> 6 blocks/CU.
// ---------------------------------------------------------------------------
__global__ __launch_bounds__(256) void mega_kernel(
    const float* __restrict__ locs4s, const int* __restrict__ oidx,
    const int* __restrict__ cellstart, int* __restrict__ knn, int n,
    const float* __restrict__ ea, const int* __restrict__ cs_eid,
    short* __restrict__ eac, int E,
    const float* __restrict__ w1A, const float* __restrict__ b1A,
    float* __restrict__ wpqA, float* __restrict__ bpqA,
    const float* __restrict__ w1B, const float* __restrict__ b1B,
    float* __restrict__ wpqB, float* __restrict__ bpqB,
    const float* __restrict__ x, const float* __restrict__ wm1,
    float* __restrict__ Rout,
    int KB, int EB)
{
  __shared__ __align__(16) char smem[4*320*8 + 4*KNN_PCAP*2];  // 23040 B
  const int bid = blockIdx.x;
  if (bid < KB) {
    knn_body(bid, (ull*)smem, (u16*)(smem + 4*320*8),
             locs4s, oidx, cellstart, knn, n);
  } else if (bid < KB + EB) {
    const int e = (bid - KB) * 256 + threadIdx.x;
    if (e < E) {
      const float* src = ea + (size_t)cs_eid[e]*16;
      short tmp[16];
#pragma unroll
      for (int u = 0; u < 4; ++u) {
        const float4 v = *(const float4*)(src + u*4);
        tmp[u*4+0] = f2bf(v.x); tmp[u*4+1] = f2bf(v.y);
        tmp[u*4+2] = f2bf(v.z); tmp[u*4+3] = f2bf(v.w);
      }
      *(short8v*)(eac + (size_t)e*16)     = *(short8v*)&tmp[0];
      *(short8v*)(eac + (size_t)e*16 + 8) = *(short8v*)&tmp[8];
    }
  } else if (bid < KB + EB + 64) {
    const int gidx = (bid - KB - EB) * 256 + threadIdx.x;
    const int l = gidx >> 13;
    const int idx = gidx & 8191;
    const float* w1 = l ? w1B : w1A;
    const float* b1 = l ? b1B : b1A;
    float* wpq = l ? wpqB : wpqA;
    float* bpq = l ? bpqB : bpqA;
    const int o = idx >> 6, i = idx & 63;
    const float a = w1[o*128 + i], b = w1[o*128 + 64 + i];
    wpq[idx] = a - b;
    wpq[128*64 + idx] = b;
    if (idx < 128) { bpq[idx] = b1[idx]; bpq[128 + idx] = 0.f; }
  } else {
    // R1 GEMM: Rout = x @ wm1^T  (wm1 pre-offset +16, ld 80); needs 18432 B
    short* As = (short*)smem;
    short* Ws = (short*)(smem + 64*72*2);
    const int tid = threadIdx.x;
    const int wave = tid >> 6, lane = tid & 63;
    const int grp = lane >> 4, li = lane & 15;
    const int m0 = (bid - KB - EB - 64) * 64;
    const int srow = tid >> 2;
    const int sc16 = (tid & 3) * 16;
    const int gr = m0 + srow;
    stage_tile_bf16(As, x + (size_t)gr*64 + sc16, srow, sc16, gr < n);
    stage_tile_bf16(Ws, wm1 + (size_t)srow*80 + sc16, srow, sc16, true);
    __syncthreads();
    f32x4 acc[4];
#pragma unroll
    for (int nt = 0; nt < 4; ++nt) acc[nt] = (f32x4)0.f;
#pragma unroll
    for (int ks = 0; ks < 2; ++ks) {
      const short8v a = *(const short8v*)&As[(wave*16 + li)*72 + ks*32 + grp*8];
#pragma unroll
      for (int nt = 0; nt < 4; ++nt) {
        const short8v b = *(const short8v*)&Ws[(nt*16 + li)*72 + ks*32 + grp*8];
        acc[nt] = __builtin_amdgcn_mfma_f32_16x16x32_bf16(a, b, acc[nt], 0, 0, 0);
      }
    }
#pragma unroll
    for (int nt = 0; nt < 4; ++nt) {
      const int ch = nt*16 + li;
#pragma unroll
      for (int j = 0; j < 4; ++j) {
        const int r = m0 + wave*16 + grp*4 + j;
        if (r < n) Rout[(size_t)r*64 + ch] = acc[nt][j];
      }
    }
  }
}

// ---------------------------------------------------------------------------
// Standalone kernels (msg1, dyn1) + combos for independent-stage merging.
// ---------------------------------------------------------------------------
__global__ __launch_bounds__(256) void static_msg_kernel(
    const float* __restrict__ R, const short* __restrict__ eac,
    const float* __restrict__ wm, const float* __restrict__ bm,
    const int* __restrict__ cs_src, const int* __restrict__ rowptr,
    float* __restrict__ agg, int n)
{
  msg_body(blockIdx.x, R, eac, wm, bm, cs_src, rowptr, agg, n);
}

__global__ __launch_bounds__(256) void dyn_mfma_kernel(
    const float* __restrict__ PQ,
    const float* __restrict__ W2, const float* __restrict__ b2,
    const int* __restrict__ knn, float* __restrict__ out, int ldo, int n)
{
  __shared__ __align__(16) char smem[64*136*2 + 4*17*136*2];
  dyn_body((short*)smem, (short*)(smem + 64*136*2), blockIdx.x,
           PQ, W2, b2, knn, out, ldo, n);
}

// combo: msg (blocks [0,SMB)) + linear (blocks [SMB, SMB+MB*4))
__global__ __launch_bounds__(256) void combo_msg_lin_kernel(
    const float* __restrict__ R, const short* __restrict__ eac,
    const float* __restrict__ wm, const float* __restrict__ bm,
    const int* __restrict__ cs_src, const int* __restrict__ rowptr,
    float* __restrict__ agg,
    const float* __restrict__ A, int lda,
    const float* __restrict__ W, int ldw, const float* __restrict__ bias,
    float* __restrict__ C, int ldc, int K, int n, int SMB, int MB)
{
  __shared__ short As[64 * 72];
  __shared__ short Ws[64 * 72];
  const int bid = blockIdx.x;
  if (bid < SMB) {
    msg_body(bid, R, eac, wm, bm, cs_src, rowptr, agg, n);
  } else {
    const int flat = bid - SMB;
    lin_body<false>(As, Ws, flat % MB, flat / MB, A, lda, W, ldw, bias,
                    C, ldc, n, K);
  }
}

// combo: fused_hR (blocks [0,MB)) + dyn conv (blocks [MB, MB+DB))
__global__ __launch_bounds__(256) void combo_hR_dyn_kernel(
    const float* __restrict__ Ain,
    const float* __restrict__ Wu, const float* __restrict__ bu,
    float* __restrict__ Hout, int ldh,
    const float* __restrict__ Wm, float* __restrict__ Rout,
    const float* __restrict__ PQ,
    const float* __restrict__ W2, const float* __restrict__ b2,
    const int* __restrict__ knn, float* __restrict__ outp, int ldo,
    int n, int MB)
{
  __shared__ __align__(16) char smem[64*136*2 + 4*17*136*2];  // 36992 B
  const int bid = blockIdx.x;
  if (bid < MB) {
    hR_body((short*)smem, (short*)(smem + 64*72*2), bid,
            Ain, Wu, bu, Hout, ldh, Wm, Rout, n);
  } else {
    dyn_body((short*)smem, (short*)(smem + 64*136*2), bid - MB,
             PQ, W2, b2, knn, outp, ldo, n);
  }
}

// ---------------------------------------------------------------------------
// Fused output stage: h3 in LDS, fu1 in LDS,
// out = [CAT,h3]@f2w[:,64:]^T + fu1@f2w[:,0:64]^T + f2b.
// ---------------------------------------------------------------------------
__global__ __launch_bounds__(256) void fusion_kernel(
    const float* __restrict__ CAT,
    const float* __restrict__ aggv,
    const float* __restrict__ wu3, const float* __restrict__ bu3,
    const float* __restrict__ f1w, const float* __restrict__ f1b,
    const float* __restrict__ f2w, const float* __restrict__ f2bias,
    float* __restrict__ out, int M)
{
  __shared__ short As[64 * 72];
  __shared__ short W1s[64 * 72];
  __shared__ short W2s[64 * 72];
  __shared__ short H3s[64 * 72];
  const int tid = threadIdx.x;
  const int wave = tid >> 6, lane = tid & 63;
  const int grp = lane >> 4, li = lane & 15;
  const int m0 = blockIdx.x * 64;
  const int srow = tid >> 2;
  const int sc16 = (tid & 3) * 16;

  // ---- phase 0: h3 tile ----
  {
    const int gr = m0 + srow;
    stage_tile_bf16(As,  aggv + (size_t)gr*64 + sc16, srow, sc16, gr < M);
    stage_tile_bf16(W1s, wu3 + (size_t)srow*64 + sc16, srow, sc16, true);
  }
  __syncthreads();
  f32x4 acc1[4], acc2[4];
#pragma unroll
  for (int nt = 0; nt < 4; ++nt) { acc1[nt] = (f32x4)0.f; acc2[nt] = (f32x4)0.f; }
#pragma unroll
  for (int ks = 0; ks < 2; ++ks) {
    const short8v a = *(const short8v*)&As[(wave*16 + li)*72 + ks*32 + grp*8];
#pragma unroll
    for (int nt = 0; nt < 4; ++nt) {
      const short8v b = *(const short8v*)&W1s[(nt*16 + li)*72 + ks*32 + grp*8];
      acc1[nt] = __builtin_amdgcn_mfma_f32_16x16x32_bf16(a, b, acc1[nt], 0, 0, 0);
    }
  }
#pragma unroll
  for (int nt = 0; nt < 4; ++nt) {
    const int ch = nt*16 + li;
    const float b = bu3[ch];
#pragma unroll
    for (int j = 0; j < 4; ++j) {
      const int row = wave*16 + grp*4 + j;
      H3s[row*72 + ch] = f2bf(fmaxf(acc1[nt][j] + b, 0.f));
    }
  }
  __syncthreads();

  // ---- main loop: 4 CAT tiles + h3 tile ----
#pragma unroll
  for (int nt = 0; nt < 4; ++nt) acc1[nt] = (f32x4)0.f;
  for (int tile = 0; tile < 5; ++tile) {
    const int kt = tile * 64;
    if (tile < 4) {
      const int gr = m0 + srow;
      stage_tile_bf16(As, CAT + (size_t)gr*320 + kt + sc16, srow, sc16, gr < M);
    }
    stage_tile_bf16(W1s, f1w + (size_t)srow*320 + kt + sc16, srow, sc16, true);
    stage_tile_bf16(W2s, f2w + (size_t)srow*384 + 64 + kt + sc16, srow, sc16, true);
    __syncthreads();
    const short* Ause = (tile < 4) ? As : H3s;
#pragma unroll
    for (int ks = 0; ks < 2; ++ks) {
      const short8v a = *(const short8v*)&Ause[(wave*16 + li)*72 + ks*32 + grp*8];
#pragma unroll
      for (int nt = 0; nt < 4; ++nt) {
        const short8v b1 = *(const short8v*)&W1s[(nt*16 + li)*72 + ks*32 + grp*8];
        const short8v b2 = *(const short8v*)&W2s[(nt*16 + li)*72 + ks*32 + grp*8];
        acc1[nt] = __builtin_amdgcn_mfma_f32_16x16x32_bf16(a, b1, acc1[nt], 0, 0, 0);
        acc2[nt] = __builtin_amdgcn_mfma_f32_16x16x32_bf16(a, b2, acc2[nt], 0, 0, 0);
      }
    }
    __syncthreads();
  }

  // ---- fu1 finish ----
  stage_tile_bf16(W1s, f2w + (size_t)srow*384 + sc16, srow, sc16, true);
#pragma unroll
  for (int nt = 0; nt < 4; ++nt) {
    const int ch = nt*16 + li;
    const float b = f1b[ch];
#pragma unroll
    for (int j = 0; j < 4; ++j) {
      const int row = wave*16 + grp*4 + j;
      As[row*72 + ch] = f2bf(fmaxf(acc1[nt][j] + b, 0.f));
    }
  }
  __syncthreads();
#pragma unroll
  for (int ks = 0; ks < 2; ++ks) {
    const short8v a = *(const short8v*)&As[(wave*16 + li)*72 + ks*32 + grp*8];
#pragma unroll
    for (int nt = 0; nt < 4; ++nt) {
      const short8v b = *(const short8v*)&W1s[(nt*16 + li)*72 + ks*32 + grp*8];
      acc2[nt] = __builtin_amdgcn_mfma_f32_16x16x32_bf16(a, b, acc2[nt], 0, 0, 0);
    }
  }
#pragma unroll
  for (int nt = 0; nt < 4; ++nt) {
    const int ch = nt*16 + li;
    const float b = f2bias[ch];
#pragma unroll
    for (int j = 0; j < 4; ++j) {
      const int gr = m0 + wave*16 + grp*4 + j;
      if (gr < M) out[(size_t)gr*64 + ch] = acc2[nt][j] + b;
    }
  }
}

// ---------------------------------------------------------------------------
// Host orchestration
// ---------------------------------------------------------------------------
extern "C" void kernel_launch(void* const* d_in, const int* in_sizes, int n_in,
                              void* d_out, int out_size, void* d_ws, size_t ws_size,
                              hipStream_t stream)
{
  const float* x   = (const float*)d_in[0];
  const int*   ei  = (const int*)d_in[1];
  const float* ea  = (const float*)d_in[2];
  const float* loc = (const float*)d_in[3];
  const float* sg_wm[3] = {(const float*)d_in[5],  (const float*)d_in[9],  (const float*)d_in[13]};
  const float* sg_bm[3] = {(const float*)d_in[6],  (const float*)d_in[10], (const float*)d_in[14]};
  const float* sg_wu[3] = {(const float*)d_in[7],  (const float*)d_in[11], (const float*)d_in[15]};
  const float* sg_bu[3] = {(const float*)d_in[8],  (const float*)d_in[12], (const float*)d_in[16]};
  const float* dg_w1[2] = {(const float*)d_in[17], (const float*)d_in[21]};
  const float* dg_b1[2] = {(const float*)d_in[18], (const float*)d_in[22]};
  const float* dg_w2[2] = {(const float*)d_in[19], (const float*)d_in[23]};
  const float* dg_b2[2] = {(const float*)d_in[20], (const float*)d_in[24]};
  const float* f1_w = (const float*)d_in[25];
  const float* f1_b = (const float*)d_in[26];
  const float* f2_w = (const float*)d_in[27];
  const float* f2_b = (const float*)d_in[28];
  float* out = (float*)d_out;

  const int n    = in_sizes[0] / 64;
  const int Etot = in_sizes[1] / 2;
  const int* srcp = ei;
  const int* dstp = ei + Etot;

  char* basep = (char*)d_ws;
  size_t cur = 0;
  auto alloc = [&](size_t bytes) -> void* {
    void* p = basep + cur;
    cur = (cur + bytes + 255) & ~(size_t)255;
    return p;
  };
  float* CAT  = (float*)alloc((size_t)n * 320 * 4);   // cols 256.. unused
  float* Rb   = (float*)alloc((size_t)n * 64 * 4);
  float* PQb  = (float*)alloc((size_t)n * 256 * 4);
  float* agg  = (float*)alloc((size_t)n * 64 * 4);
  float* wpq[2];
  float* bpq[2];
  wpq[0] = (float*)alloc(256 * 64 * 4);  bpq[0] = (float*)alloc(256 * 4);
  wpq[1] = (float*)alloc(256 * 64 * 4);  bpq[1] = (float*)alloc(256 * 4);
  int* knnb   = (int*)alloc((size_t)n * 16 * 4);
  int* zeros     = (int*)alloc((size_t)(2*KNN_NC + 2*n) * 4);
  int* cellcount = zeros;
  int* cellfill  = zeros + KNN_NC;
  int* deg       = zeros + 2*KNN_NC;
  int* dfill     = zeros + 2*KNN_NC + n;
  int* cellstart = (int*)alloc((size_t)(KNN_NC + 1) * 4);
  int* cellidb   = (int*)alloc((size_t)n * 4);
  float* locs4s  = (float*)alloc((size_t)n * 4 * 4);
  int* oidx      = (int*)alloc((size_t)n * 4);
  int* rowptr    = (int*)alloc((size_t)(n + 1) * 4);
  int* cs_src    = (int*)alloc((size_t)Etot * 4);
  int* cs_eid    = (int*)alloc((size_t)Etot * 4);
  short* ea_csr  = (short*)alloc((size_t)Etot * 16 * 2);   // bf16
  (void)ws_size; (void)n_in; (void)out_size;

  const int nbE = (Etot + 255) / 256;
  const int mb = (n + 63) / 64;
  const int smb = (n + 4*TPW_S - 1) / (4*TPW_S);
  const int db = (n + 4*TPW - 1) / (4*TPW);

  hipMemsetAsync(zeros, 0, (size_t)(2*KNN_NC + 2*n) * 4, stream);
  count2_kernel<<<nbE, 256, 0, stream>>>(loc, cellcount, cellidb, n,
                                         dstp, deg, Etot);
  scan2_kernel<<<2, 1024, 0, stream>>>(cellcount, cellstart, KNN_NC,
                                       (KNN_NC + 1023) / 1024,
                                       deg, rowptr, n, (n + 1023) / 1024);
  scatter2_kernel<<<nbE, 256, 0, stream>>>(loc, cellidb, cellstart, cellfill,
                                           locs4s, oidx, n,
                                           srcp, dstp, rowptr, dfill,
                                           cs_src, cs_eid, Etot);
  const int KB = (n + 3) / 4;
  const int EB = (Etot + 255) / 256;      // one edge per thread
  mega_kernel<<<KB + EB + 64 + mb, 256, 0, stream>>>(
      locs4s, oidx, cellstart, knnb, n,
      ea, cs_eid, ea_csr, Etot,
      dg_w1[0], dg_b1[0], wpq[0], bpq[0],
      dg_w1[1], dg_b1[1], wpq[1], bpq[1],
      x, sg_wm[0] + 16, Rb,
      KB, EB);

  // msg1: Rb -> agg
  static_msg_kernel<<<smb, 256, 0, stream>>>(Rb, ea_csr, sg_wm[0], sg_bm[0],
                                             cs_src, rowptr, agg, n);
  // hR1: agg -> h1(CAT+0), R2(Rb)
  combo_hR_dyn_kernel<<<mb, 256, 0, stream>>>(
      agg, sg_wu[0], sg_bu[0], CAT + 0, 320, sg_wm[1] + 16, Rb,
      nullptr, nullptr, nullptr, nullptr, nullptr, 0, n, mb);  // hR-only grid

  // combo1: msg2 (Rb->agg) + PQlin0 (CAT+0 -> PQb)
  combo_msg_lin_kernel<<<smb + mb*4, 256, 0, stream>>>(
      Rb, ea_csr, sg_wm[1], sg_bm[1], cs_src, rowptr, agg,
      CAT + 0, 320, wpq[0], 64, bpq[0], PQb, 256, 64, n, smb, mb);

  // combo2: hR2 (agg -> h2(CAT+192), R3(Rb)) + dyn0 (PQb -> g1(CAT+64))
  combo_hR_dyn_kernel<<<mb + db, 256, 0, stream>>>(
      agg, sg_wu[1], sg_bu[1], CAT + 192, 320, sg_wm[2] + 16, Rb,
      PQb, dg_w2[0], dg_b2[0], knnb, CAT + 64, 320, n, mb);

  // combo3: msg3 (Rb->agg) + PQlin1 (g1 -> PQb)
  combo_msg_lin_kernel<<<smb + mb*4, 256, 0, stream>>>(
      Rb, ea_csr, sg_wm[2], sg_bm[2], cs_src, rowptr, agg,
      CAT + 64, 320, wpq[1], 64, bpq[1], PQb, 256, 64, n, smb, mb);

  // dyn1: PQb -> g2(CAT+128)
  dyn_mfma_kernel<<<db, 256, 0, stream>>>(PQb, dg_w2[1], dg_b2[1],
                                          knnb, CAT + 128, 320, n);

  // fused output stage (includes h3 from agg)
  fusion_kernel<<<mb, 256, 0, stream>>>(CAT, agg, sg_wu[2], sg_bu[2],
                                        f1_w, f1_b, f2_w, f2_b, out, n);
}